// Round 4
// baseline (2284.422 us; speedup 1.0000x reference)
//
#include <hip/hip_runtime.h>
#include <hip/hip_bf16.h>
#include <math.h>

// B=32 graphs, N=256 nodes/graph, D=128.
#define DD   128
#define NPG  256
#define NGR  32
#define TTOT 8192
#define LOG2E  1.4426950408889634f
#define LOG2E2 2.8853900817779268f   // 2*log2(e)
#define KSTRIDE 264                   // LDS floats per transposed key row
#define SSTR    268                   // spartS row stride
#define H2A(j)  ((j) + (((j)>>5)<<3))   // stagger: chunk base -> bank chunk*8
#define PAD16(j) ((j) + (((j)>>4)<<2))  // q/v pad: d -> d + (d>>4)*4

__device__ __forceinline__ float dot4(float4 a, float4 b){
  return a.x*b.x + a.y*b.y + a.z*b.z + a.w*b.w;
}
// ---- DPP cross-lane (VALU pipe; keeps ds_bpermute off critical chains) ----
template<int CTRL, int RMASK>
__device__ __forceinline__ float upd_f(float oldv, float x){
  return __int_as_float(__builtin_amdgcn_update_dpp(
      __float_as_int(oldv), __float_as_int(x), CTRL, RMASK, 0xf, false));
}
__device__ __forceinline__ float dpp_xor1(float x){
  return __int_as_float(__builtin_amdgcn_mov_dpp(__float_as_int(x), 0xB1, 0xf, 0xf, false));
}
__device__ __forceinline__ float dpp_xor2(float x){
  return __int_as_float(__builtin_amdgcn_mov_dpp(__float_as_int(x), 0x4E, 0xf, 0xf, false));
}
__device__ __forceinline__ float quad_sum_dpp(float x){
  float s = x + dpp_xor1(x);
  return s + dpp_xor2(s);
}
__device__ __forceinline__ float dpp_wave_sum(float x){
  x += upd_f<0x111,0xf>(0.f, x);   // row_shr:1
  x += upd_f<0x112,0xf>(0.f, x);   // row_shr:2
  x += upd_f<0x114,0xf>(0.f, x);   // row_shr:4
  x += upd_f<0x118,0xf>(0.f, x);   // row_shr:8
  x += upd_f<0x142,0xa>(0.f, x);   // row_bcast15
  x += upd_f<0x143,0xc>(0.f, x);   // row_bcast31
  return __uint_as_float(__builtin_amdgcn_readlane(__float_as_uint(x), 63));
}
__device__ __forceinline__ float dpp_wave_max(float x){
  const float NI = -INFINITY;
  x = fmaxf(x, upd_f<0x111,0xf>(NI, x));
  x = fmaxf(x, upd_f<0x112,0xf>(NI, x));
  x = fmaxf(x, upd_f<0x114,0xf>(NI, x));
  x = fmaxf(x, upd_f<0x118,0xf>(NI, x));
  x = fmaxf(x, upd_f<0x142,0xa>(NI, x));
  x = fmaxf(x, upd_f<0x143,0xc>(NI, x));
  return __uint_as_float(__builtin_amdgcn_readlane(__float_as_uint(x), 63));
}
__device__ __forceinline__ float sigfast(float x){
  return __builtin_amdgcn_rcpf(1.f + __builtin_amdgcn_exp2f(-x*LOG2E));
}
__device__ __forceinline__ float tanhfast(float y){
  return 1.f - 2.f*__builtin_amdgcn_rcpf(1.f + __builtin_amdgcn_exp2f(y*LOG2E2));
}

// ---------------- Kernel 1: parallel precompute (R9/R12 SCALAR version) ----------------
// SCALAR mm_tile accumulation order is part of the validated-numerics contract
// (R10's float4 reorder flipped a near-tie argmax -> tour divergence). DO NOT vectorize.
// keysE[d][n] = exp(2 * l2norm(relu(emb@Wk1.T+bk1)@Wk2.T+bk2)[n][d])  [128][8192] TRANSPOSED
// gi_all = emb@W_ih.T + b_ih                                          [8192,384]

__device__ __forceinline__ void load_w128(float* Ws, const float* __restrict__ W, int t){
  const float4* src = (const float4*)W;
  #pragma unroll
  for (int m=0;m<16;m++){
    int idx = m*256+t; int r = idx>>5, c4 = idx&31;
    float4 val = src[idx];
    float* dst = &Ws[r*129 + c4*4];
    dst[0]=val.x; dst[1]=val.y; dst[2]=val.z; dst[3]=val.w;
  }
}

__device__ __forceinline__ void mm_tile(const float* __restrict__ inS, const float* __restrict__ Ws,
                                        float acc[4][4], int jg, int ng){
  #pragma unroll
  for(int r=0;r<4;r++)
    #pragma unroll
    for(int c=0;c<4;c++) acc[r][c]=0.f;
  #pragma unroll 4
  for (int k=0;k<128;k++){
    float w[4], x[4];
    #pragma unroll
    for (int r=0;r<4;r++) w[r] = Ws[(jg*4+r)*129+k];
    #pragma unroll
    for (int c=0;c<4;c++) x[c] = inS[(ng*4+c)*129+k];
    #pragma unroll
    for (int r=0;r<4;r++)
      #pragma unroll
      for (int c=0;c<4;c++) acc[r][c] += w[r]*x[c];
  }
}

__global__ __launch_bounds__(256) void precompute_kernel(
    const float* __restrict__ emb,
    const float* __restrict__ Wk1, const float* __restrict__ bk1,
    const float* __restrict__ Wk2, const float* __restrict__ bk2,
    const float* __restrict__ Wih, const float* __restrict__ bih,
    float* __restrict__ keysE, float* __restrict__ giall)
{
  __shared__ __align__(16) float xs[32*129];
  __shared__ __align__(16) float Ws[128*129];
  __shared__ __align__(16) float hs[32*129];
  __shared__ __align__(16) float os[32*129];
  __shared__ float nrm[32];
  const int t  = threadIdx.x;
  const int n0 = blockIdx.x * 32;
  const int ng = t & 7, jg = t >> 3;

  {
    const float4* src = (const float4*)emb + (size_t)n0*32;
    #pragma unroll
    for (int m=0;m<4;m++){
      int idx = m*256+t; int n = idx>>5, c4 = idx&31;
      float4 val = src[idx];
      float* dst = &xs[n*129 + c4*4];
      dst[0]=val.x; dst[1]=val.y; dst[2]=val.z; dst[3]=val.w;
    }
  }
  load_w128(Ws, Wk1, t);
  __syncthreads();
  {
    float acc[4][4];
    mm_tile(xs, Ws, acc, jg, ng);
    #pragma unroll
    for (int r=0;r<4;r++){
      float bb = bk1[jg*4+r];
      #pragma unroll
      for (int c=0;c<4;c++) hs[(ng*4+c)*129 + jg*4+r] = fmaxf(acc[r][c]+bb, 0.f);
    }
  }
  __syncthreads();
  load_w128(Ws, Wk2, t);
  __syncthreads();
  {
    float acc[4][4];
    mm_tile(hs, Ws, acc, jg, ng);
    #pragma unroll
    for (int r=0;r<4;r++){
      float bb = bk2[jg*4+r];
      #pragma unroll
      for (int c=0;c<4;c++) os[(ng*4+c)*129 + jg*4+r] = acc[r][c]+bb;
    }
  }
  __syncthreads();
  if (t<32){
    float ss=0.f;
    for (int j=0;j<128;j++){ float x = os[t*129+j]; ss += x*x; }
    nrm[t] = fmaxf(sqrtf(ss), 1e-12f);
  }
  __syncthreads();
  // transposed E-keys: keysE[d][n] = exp(2*K)
  #pragma unroll
  for (int m=0;m<16;m++){
    int idx = m*256+t; int nl = idx & 31, d = idx >> 5;
    float kk = os[nl*129 + d] / nrm[nl];
    keysE[(size_t)d*TTOT + n0 + nl] = __builtin_amdgcn_exp2f(kk * LOG2E2);
  }
  for (int c=0;c<3;c++){
    __syncthreads();
    load_w128(Ws, Wih + c*16384, t);
    __syncthreads();
    float acc[4][4];
    mm_tile(xs, Ws, acc, jg, ng);
    #pragma unroll
    for (int r=0;r<4;r++){
      float bb = bih[c*128 + jg*4+r];
      #pragma unroll
      for (int cc=0;cc<4;cc++)
        giall[(size_t)(n0 + ng*4+cc)*384 + c*128 + jg*4 + r] = acc[r][cc] + bb;
    }
  }
}

// ---------------- Kernel 2: sequential decode ----------------
// R16: 32 blocks x 576 threads (NINE waves); 255 steps; four barriers/step.
// Waves 0-7 run the R12-validated phases UNCHANGED (bit-identical math):
//   phase A -> B1 -> qh -> B2 -> q -> B3 -> score -> Bs1 -> combine(argmax+gi).
// Wave 8 is a dedicated "service wave" that absorbs ALL off-critical-path
// side jobs that previously made specific waves barrier stragglers:
//   - tours store + keys-column swap (was waves 2-3/6, serialized vs phase A)
//   - deferred map update after B1 (was wave 7)
//   - es/S/lp softmax tail (was computed REDUNDANTLY by every wave: 4 exp2 +
//     6-DPP wave_sum ~100cy on every wave's combine tail; only 1 lane used it)
// Wave 8 replicates the combine argmax bit-exactly (same LDS reads, same
// i=0..7 order, same first-max tie-break) so its cur/es/S match waves 0-7.
// NO new persistent per-thread state (R13/R14 lesson: this kernel is at the
// 128-VGPR boundary; anything persistent spills). giall warm removed (R15: neutral).

__global__ __launch_bounds__(576, 2) void decode_kernel(
    const float* __restrict__ emb,
    const float* __restrict__ keysE, const float* __restrict__ giall,
    const float* __restrict__ Whh, const float* __restrict__ bhh,
    const float* __restrict__ Wq1, const float* __restrict__ bq1,
    const float* __restrict__ Wq2, const float* __restrict__ bq2,
    const float* __restrict__ v,   const float* __restrict__ Wh,
    const float* __restrict__ bh,  const int* __restrict__ start_nodes,
    float* __restrict__ tours_o, float* __restrict__ lp_o)
{
  __shared__ __align__(16) float keys_s[128*KSTRIDE];  // 132 KB, transposed E-keys
  __shared__ __align__(16) float h_s[2][160];          // staggered (H2A)
  __shared__ __align__(16) float qh_s[160];            // staggered (H2A)
  __shared__ __align__(16) float q_s[160];             // PAD16 (raw q), also gctx scratch
  __shared__ __align__(16) float v_sp[160];            // PAD16 layout, -2*v
  __shared__ __align__(16) float spartS[8*SSTR];       // score partials (+init scratch)
  __shared__ int col2node_s[256], node2col_s[256];
  __shared__ float red2[8];

  const int t = threadIdx.x;
  const int b = blockIdx.x;
  const int g  = t >> 2, s3 = t & 3;   // 128 groups x 4 lanes (matvec, waves 0-7)
  const int w  = t >> 6, L  = t & 63;
  const int oct = L & 7, dgrp = L >> 3; // score: col-octet, dim-group
  const bool mainw = (t < 512);         // waves 0-7; wave 8 = service wave
  const int gE = mainw ? g : 0;         // safe row index for wave 8's dummy preloads

  // register weights: Whh rows g,128+g,256+g (chunk s3*32); Wq1/Wq2 row g
  float4 whh4[3][8], wq14[8], wq24[8];
  {
    const float4* w0  = (const float4*)(Whh + (size_t)(gE      )*128 + s3*32);
    const float4* w1  = (const float4*)(Whh + (size_t)(128 + gE)*128 + s3*32);
    const float4* w2  = (const float4*)(Whh + (size_t)(256 + gE)*128 + s3*32);
    const float4* q1p = (const float4*)(Wq1 + (size_t)gE*128 + s3*32);
    const float4* q2p = (const float4*)(Wq2 + (size_t)gE*128 + s3*32);
    #pragma unroll
    for (int i=0;i<8;i++){
      whh4[0][i]=w0[i]; whh4[1][i]=w1[i]; whh4[2][i]=w2[i];
      wq14[i]=q1p[i];   wq24[i]=q2p[i];
    }
  }
  const float br = bhh[gE], bz = bhh[128+gE], bn = bhh[256+gE];
  const float b1g = bq1[gE], b2g = bq2[gE];

  if (t<128) v_sp[PAD16(t)] = -2.f * v[t];
  if (t<256){ col2node_s[t] = t; node2col_s[t] = t; }
  if (mainw){ // stage transposed E-keys: coalesced per d-row (exact R12 indexing)
    #pragma unroll
    for (int m=0;m<16;m++){
      int idx = m*512 + t; int d = idx>>6, q = idx&63;
      *(float4*)(keys_s + d*KSTRIDE + q*4) =
        *(const float4*)(keysE + (size_t)d*TTOT + b*256 + q*4);
    }
  }
  if (mainw){ // graph-context partial sums (4 parts x 64 nodes)
    int d = t & 127, part = t >> 7;
    float a = 0.f;
    const float* base = emb + (size_t)(b*256 + part*64)*128 + d;
    for (int i=0;i<64;i++) a += base[(size_t)i*128];
    spartS[part*128+d] = a;
  }
  int cur = start_nodes[b];
  __syncthreads();
  if (t<128){
    float a = 0.f;
    #pragma unroll
    for (int p=0;p<4;p++) a += spartS[p*128+t];
    q_s[t] = a * (1.f/256.f);          // gctx temp (plain idx, init only)
  }
  __syncthreads();
  if (t<128){ // hidden0 = gctx@Wh.T + bh  (write staggered)
    float a = bh[t];
    const float* wr = Wh + (size_t)t*128;
    for (int k=0;k<128;k++) a += wr[k]*q_s[k];
    h_s[0][H2A(t)] = a;
  }
  { // sv = sum(v)
    float xv = (t<128) ? v[t] : 0.f;
    float tot = dpp_wave_sum(xv);
    if (L==0 && w<8) red2[w] = tot;
  }
  __syncthreads();
  float sv = 0.f;
  #pragma unroll
  for (int i=0;i<8;i++) sv += red2[i];

  // gi prefetch for step 0
  float gir=0.f, giz=0.f, gin=0.f;
  if (s3==0 && mainw){
    const float* gp = giall + (size_t)cur*384 + g;
    gir = gp[0]; giz = gp[128]; gin = gp[256];
  }

  for (int step=0; step<255; step++){
    const int par = step & 1;
    const int V   = 255 - step;          // valid count after removing cur
    const int curl = cur - b*256;

    // ---- wave 8: tours store + swap-remove cur's keys column (2 rows/lane;
    //      reads PRE-update map; race-free: score(s-1) readers all passed
    //      Bs1, and nothing touches keys_s until score(s) after B3) ----
    if (w == 8){
      if (L == 0) tours_o[b*256+step] = (float)cur;
      int px = node2col_s[curl];
      keys_s[L*KSTRIDE + px]       = keys_s[L*KSTRIDE + V];
      keys_s[(L+64)*KSTRIDE + px]  = keys_s[(L+64)*KSTRIDE + V];
    }

    // ---- phase A: gh dots + fused GRU -> h_s[par^1] (waves 0-7) ----
    if (mainw){
      float a0=0.f,a1=0.f,a2=0.f;
      const float4* hc4 = (const float4*)(h_s[par] + s3*40);
      #pragma unroll
      for (int i=0;i<8;i++){
        float4 hv = hc4[i];
        a0 += dot4(whh4[0][i], hv);
        a1 += dot4(whh4[1][i], hv);
        a2 += dot4(whh4[2][i], hv);
      }
      a0 = quad_sum_dpp(a0);
      a1 = quad_sum_dpp(a1);
      a2 = quad_sum_dpp(a2);
      if (s3==0){
        float r = sigfast(gir + a0 + br);
        float z = sigfast(giz + a1 + bz);
        float n = tanhfast(gin + r*(a2 + bn));
        h_s[par^1][H2A(g)] = (1.f-z)*n + z*h_s[par][H2A(g)];
      }
    }
    __syncthreads();                                   // B1

    // ---- deferred index-map update (wave 8 lane 0; race-free: all prev-step
    //      combine reads of col2node_s completed before B1) ----
    if (t == 512){
      int px = node2col_s[curl];
      int ln = col2node_s[V];
      col2node_s[px] = ln;
      node2col_s[ln] = px;
    }

    if (mainw){ // qh = relu(h@Wq1.T + bq1)
      float a=0.f;
      const float4* hc4 = (const float4*)(h_s[par^1] + s3*40);
      #pragma unroll
      for (int i=0;i<8;i++) a += dot4(wq14[i], hc4[i]);
      a = quad_sum_dpp(a);
      if (s3==0) qh_s[H2A(g)] = fmaxf(a + b1g, 0.f);
    }
    __syncthreads();                                   // B2

    if (mainw){ // q_raw = qh@Wq2.T + bq2 (PAD16 store) ; per-wave ssq via DPP
      float a=0.f;
      const float4* qc4 = (const float4*)(qh_s + s3*40);
      #pragma unroll
      for (int i=0;i<8;i++) a += dot4(wq24[i], qc4[i]);
      a = quad_sum_dpp(a);
      float qval = a + b2g;
      if (s3==0) q_s[PAD16(g)] = qval;
      float ssp = (s3==0) ? qval*qval : 0.f;
      float tot = dpp_wave_sum(ssp);
      if (L==0) red2[w] = tot;
    }
    __syncthreads();                                   // B3

    // ---- score: wave w -> cols 32w..32w+31 (whole-wave skip when 32w >= V;
    //      wave 8 never scores since 256 >= V) ----
    if (32*w < V){
      float ss = 0.f;
      #pragma unroll
      for (int i=0;i<8;i++) ss += red2[i];
      float rn = 1.f / fmaxf(sqrtf(ss), 1e-12f);
      const float* kbase = keys_s + dgrp*16*KSTRIDE + 32*w + oct*4;
      const float* qb    = q_s  + dgrp*20;
      const float* vbase = v_sp + dgrp*20;
      float4 acc = {0.f,0.f,0.f,0.f};
      #pragma unroll
      for (int jj=0;jj<16;jj++){
        float eqj = __builtin_amdgcn_exp2f(qb[jj] * rn * LOG2E2);
        float vj  = vbase[jj];
        float4 K = *(const float4*)(kbase + jj*KSTRIDE);
        float r0 = __builtin_amdgcn_rcpf(fmaf(K.x, eqj, 1.f));
        float r1 = __builtin_amdgcn_rcpf(fmaf(K.y, eqj, 1.f));
        float r2 = __builtin_amdgcn_rcpf(fmaf(K.z, eqj, 1.f));
        float r3 = __builtin_amdgcn_rcpf(fmaf(K.w, eqj, 1.f));
        acc.x = fmaf(vj, r0, acc.x);
        acc.y = fmaf(vj, r1, acc.y);
        acc.z = fmaf(vj, r2, acc.z);
        acc.w = fmaf(vj, r3, acc.w);
      }
      *(float4*)(spartS + dgrp*SSTR + 32*w + oct*4) = acc;
    }
    __syncthreads();                                   // Bs1

    // ---- combine: EVERY wave (incl. 8) reduces all 256 cols in the exact
    //      R12 order; every lane learns argmax -> no Bs2, no tail round-trip.
    //      es/S/lp moved to wave 8 ONLY (was redundant on all waves). ----
    {
      const float* sp = spartS + 4*L;
      float sx=0.f, sy=0.f, sz=0.f, sw=0.f;
      #pragma unroll
      for (int i=0;i<8;i++){
        float4 p = *(const float4*)(sp + i*SSTR);
        sx += p.x; sy += p.y; sz += p.z; sw += p.w;
      }
      int c0 = 4*L;
      float vx = (c0+0 < V) ? sv+sx : -INFINITY;
      float vy = (c0+1 < V) ? sv+sy : -INFINITY;
      float vz = (c0+2 < V) ? sv+sz : -INFINITY;
      float vw = (c0+3 < V) ? sv+sw : -INFINITY;
      float bm = vx; int bc = c0;                 // first-max tie-break
      if (vy > bm){ bm=vy; bc=c0+1; }
      if (vz > bm){ bm=vz; bc=c0+2; }
      if (vw > bm){ bm=vw; bc=c0+3; }
      float m = dpp_wave_max(bm);
      unsigned long long mk = __ballot(bm == m);
      int flane = __ffsll(mk) - 1;                // lowest lane = lowest col
      int besti = __builtin_amdgcn_readlane(bc, flane);
      cur = b*256 + col2node_s[besti];            // read pre-next-update map
      if (s3==0 && mainw){   // prefetch next gi (consumed in next phase A)
        const float* gp = giall + (size_t)cur*384 + g;
        gir = gp[0]; giz = gp[128]; gin = gp[256];
      }
      if (w == 8){   // softmax tail, wave 8 only (bit-identical es/S to R12)
        float es = __builtin_amdgcn_exp2f((vx-m)*LOG2E) + __builtin_amdgcn_exp2f((vy-m)*LOG2E)
                 + __builtin_amdgcn_exp2f((vz-m)*LOG2E) + __builtin_amdgcn_exp2f((vw-m)*LOG2E);
        float S = dpp_wave_sum(es);
        if (L == 1) lp_o[b*255+step] = logf(1.f/S + 1e-10f);
      }
    }
    // no barrier: next step's wave-8 swap / phase-A touch no combine-read state
  }
  if (t==0) tours_o[b*256+255] = (float)cur;

  (void)oct;
}

extern "C" void kernel_launch(void* const* d_in, const int* in_sizes, int n_in,
                              void* d_out, int out_size, void* d_ws, size_t ws_size,
                              hipStream_t stream) {
  const float* emb  = (const float*)d_in[0];
  const int*   startn = (const int*)d_in[1];
  const float* Wq1 = (const float*)d_in[3];  const float* bq1 = (const float*)d_in[4];
  const float* Wq2 = (const float*)d_in[5];  const float* bq2 = (const float*)d_in[6];
  const float* Wk1 = (const float*)d_in[7];  const float* bk1 = (const float*)d_in[8];
  const float* Wk2 = (const float*)d_in[9];  const float* bk2 = (const float*)d_in[10];
  const float* Wih = (const float*)d_in[11]; const float* Whh = (const float*)d_in[12];
  const float* bih = (const float*)d_in[13]; const float* bhh = (const float*)d_in[14];
  const float* v   = (const float*)d_in[15]; const float* Wh  = (const float*)d_in[16];
  const float* bh  = (const float*)d_in[17];

  float* keysE = (float*)d_ws;               // exp(2*keys) TRANSPOSED [128][8192]
  float* giall = keysE + (size_t)TTOT*DD;    // [8192*384]

  float* outp = (float*)d_out;   // tours [32*256] then log_probs [32*255]

  precompute_kernel<<<256, 256, 0, stream>>>(emb, Wk1, bk1, Wk2, bk2, Wih, bih, keysE, giall);
  decode_kernel<<<NGR, 576, 0, stream>>>(emb, keysE, giall, Whh, bhh, Wq1, bq1, Wq2, bq2,
                                         v, Wh, bh, startn, outp, outp + TTOT);
}

// Round 5
// 923.338 us; speedup vs baseline: 2.4741x; 2.4741x over previous
//
#include <hip/hip_runtime.h>
#include <hip/hip_bf16.h>
#include <math.h>

// B=32 graphs, N=256 nodes/graph, D=128.
#define DD   128
#define NPG  256
#define NGR  32
#define TTOT 8192
#define LOG2E  1.4426950408889634f
#define LOG2E2 2.8853900817779268f   // 2*log2(e)
#define KSTRIDE 264                   // LDS floats per transposed key row
#define SSTR    268                   // spartS row stride
#define H2A(j)  ((j) + (((j)>>5)<<3))   // stagger: chunk base -> bank chunk*8
#define PAD16(j) ((j) + (((j)>>4)<<2))  // q/v pad: d -> d + (d>>4)*4

__device__ __forceinline__ float dot4(float4 a, float4 b){
  return a.x*b.x + a.y*b.y + a.z*b.z + a.w*b.w;
}
// ---- DPP cross-lane (VALU pipe; keeps ds_bpermute off critical chains) ----
template<int CTRL, int RMASK>
__device__ __forceinline__ float upd_f(float oldv, float x){
  return __int_as_float(__builtin_amdgcn_update_dpp(
      __float_as_int(oldv), __float_as_int(x), CTRL, RMASK, 0xf, false));
}
__device__ __forceinline__ float dpp_xor1(float x){
  return __int_as_float(__builtin_amdgcn_mov_dpp(__float_as_int(x), 0xB1, 0xf, 0xf, false));
}
__device__ __forceinline__ float dpp_xor2(float x){
  return __int_as_float(__builtin_amdgcn_mov_dpp(__float_as_int(x), 0x4E, 0xf, 0xf, false));
}
__device__ __forceinline__ float quad_sum_dpp(float x){
  float s = x + dpp_xor1(x);
  return s + dpp_xor2(s);
}
__device__ __forceinline__ float dpp_wave_sum(float x){
  x += upd_f<0x111,0xf>(0.f, x);   // row_shr:1
  x += upd_f<0x112,0xf>(0.f, x);   // row_shr:2
  x += upd_f<0x114,0xf>(0.f, x);   // row_shr:4
  x += upd_f<0x118,0xf>(0.f, x);   // row_shr:8
  x += upd_f<0x142,0xa>(0.f, x);   // row_bcast15
  x += upd_f<0x143,0xc>(0.f, x);   // row_bcast31
  return __uint_as_float(__builtin_amdgcn_readlane(__float_as_uint(x), 63));
}
__device__ __forceinline__ float dpp_wave_max(float x){
  const float NI = -INFINITY;
  x = fmaxf(x, upd_f<0x111,0xf>(NI, x));
  x = fmaxf(x, upd_f<0x112,0xf>(NI, x));
  x = fmaxf(x, upd_f<0x114,0xf>(NI, x));
  x = fmaxf(x, upd_f<0x118,0xf>(NI, x));
  x = fmaxf(x, upd_f<0x142,0xa>(NI, x));
  x = fmaxf(x, upd_f<0x143,0xc>(NI, x));
  return __uint_as_float(__builtin_amdgcn_readlane(__float_as_uint(x), 63));
}
__device__ __forceinline__ float sigfast(float x){
  return __builtin_amdgcn_rcpf(1.f + __builtin_amdgcn_exp2f(-x*LOG2E));
}
__device__ __forceinline__ float tanhfast(float y){
  return 1.f - 2.f*__builtin_amdgcn_rcpf(1.f + __builtin_amdgcn_exp2f(y*LOG2E2));
}

// ---------------- Kernel 1: parallel precompute (R9/R12 SCALAR version) ----------------
// SCALAR mm_tile accumulation order is part of the validated-numerics contract
// (R10's float4 reorder flipped a near-tie argmax -> tour divergence). DO NOT vectorize.
// keysE[d][n] = exp(2 * l2norm(relu(emb@Wk1.T+bk1)@Wk2.T+bk2)[n][d])  [128][8192] TRANSPOSED
// gi_all = emb@W_ih.T + b_ih                                          [8192,384]

__device__ __forceinline__ void load_w128(float* Ws, const float* __restrict__ W, int t){
  const float4* src = (const float4*)W;
  #pragma unroll
  for (int m=0;m<16;m++){
    int idx = m*256+t; int r = idx>>5, c4 = idx&31;
    float4 val = src[idx];
    float* dst = &Ws[r*129 + c4*4];
    dst[0]=val.x; dst[1]=val.y; dst[2]=val.z; dst[3]=val.w;
  }
}

__device__ __forceinline__ void mm_tile(const float* __restrict__ inS, const float* __restrict__ Ws,
                                        float acc[4][4], int jg, int ng){
  #pragma unroll
  for(int r=0;r<4;r++)
    #pragma unroll
    for(int c=0;c<4;c++) acc[r][c]=0.f;
  #pragma unroll 4
  for (int k=0;k<128;k++){
    float w[4], x[4];
    #pragma unroll
    for (int r=0;r<4;r++) w[r] = Ws[(jg*4+r)*129+k];
    #pragma unroll
    for (int c=0;c<4;c++) x[c] = inS[(ng*4+c)*129+k];
    #pragma unroll
    for (int r=0;r<4;r++)
      #pragma unroll
      for (int c=0;c<4;c++) acc[r][c] += w[r]*x[c];
  }
}

__global__ __launch_bounds__(256) void precompute_kernel(
    const float* __restrict__ emb,
    const float* __restrict__ Wk1, const float* __restrict__ bk1,
    const float* __restrict__ Wk2, const float* __restrict__ bk2,
    const float* __restrict__ Wih, const float* __restrict__ bih,
    float* __restrict__ keysE, float* __restrict__ giall)
{
  __shared__ __align__(16) float xs[32*129];
  __shared__ __align__(16) float Ws[128*129];
  __shared__ __align__(16) float hs[32*129];
  __shared__ __align__(16) float os[32*129];
  __shared__ float nrm[32];
  const int t  = threadIdx.x;
  const int n0 = blockIdx.x * 32;
  const int ng = t & 7, jg = t >> 3;

  {
    const float4* src = (const float4*)emb + (size_t)n0*32;
    #pragma unroll
    for (int m=0;m<4;m++){
      int idx = m*256+t; int n = idx>>5, c4 = idx&31;
      float4 val = src[idx];
      float* dst = &xs[n*129 + c4*4];
      dst[0]=val.x; dst[1]=val.y; dst[2]=val.z; dst[3]=val.w;
    }
  }
  load_w128(Ws, Wk1, t);
  __syncthreads();
  {
    float acc[4][4];
    mm_tile(xs, Ws, acc, jg, ng);
    #pragma unroll
    for (int r=0;r<4;r++){
      float bb = bk1[jg*4+r];
      #pragma unroll
      for (int c=0;c<4;c++) hs[(ng*4+c)*129 + jg*4+r] = fmaxf(acc[r][c]+bb, 0.f);
    }
  }
  __syncthreads();
  load_w128(Ws, Wk2, t);
  __syncthreads();
  {
    float acc[4][4];
    mm_tile(hs, Ws, acc, jg, ng);
    #pragma unroll
    for (int r=0;r<4;r++){
      float bb = bk2[jg*4+r];
      #pragma unroll
      for (int c=0;c<4;c++) os[(ng*4+c)*129 + jg*4+r] = acc[r][c]+bb;
    }
  }
  __syncthreads();
  if (t<32){
    float ss=0.f;
    for (int j=0;j<128;j++){ float x = os[t*129+j]; ss += x*x; }
    nrm[t] = fmaxf(sqrtf(ss), 1e-12f);
  }
  __syncthreads();
  // transposed E-keys: keysE[d][n] = exp(2*K)
  #pragma unroll
  for (int m=0;m<16;m++){
    int idx = m*256+t; int nl = idx & 31, d = idx >> 5;
    float kk = os[nl*129 + d] / nrm[nl];
    keysE[(size_t)d*TTOT + n0 + nl] = __builtin_amdgcn_exp2f(kk * LOG2E2);
  }
  for (int c=0;c<3;c++){
    __syncthreads();
    load_w128(Ws, Wih + c*16384, t);
    __syncthreads();
    float acc[4][4];
    mm_tile(xs, Ws, acc, jg, ng);
    #pragma unroll
    for (int r=0;r<4;r++){
      float bb = bih[c*128 + jg*4+r];
      #pragma unroll
      for (int cc=0;cc<4;cc++)
        giall[(size_t)(n0 + ng*4+cc)*384 + c*128 + jg*4 + r] = acc[r][cc] + bb;
    }
  }
}

// ---------------- Kernel 2: sequential decode ----------------
// R17 = exact R12 structure (32 blocks x 512 threads, 4 barriers/step) + two
// bit-identical simplifications found by algebra, NOT new machinery:
//  (1) px == besti identity: the swap's old px = node2col[col2node[besti]]
//      is the identity (inverse bijections). Carry besti forward in a
//      wave-uniform register (px_cur, SGPR -> zero VGPR cost). This deletes
//      TWO dependent ~120cy LDS lookups from waves 2-3's pre-phase-A chain
//      (the B1 straggler) and makes node2col_s completely unread -> deleted.
//      Map update shrinks to col2node_s[px_cur] = col2node_s[V].
//  (2) es/S/lp softmax tail computed by wave 5 ONLY (it was redundant on all
//      8 waves; only wave 5 lane 0 consumed it). Wave 5's own computation is
//      untouched -> lp bit-identical.
// Geometry/VGPR lessons (R13/R14/R16): 512 threads + lb(512,2) + no new
// persistent per-LANE state are hard constraints (spill cliff at 128 VGPR).

__global__ __launch_bounds__(512, 2) void decode_kernel(
    const float* __restrict__ emb,
    const float* __restrict__ keysE, const float* __restrict__ giall,
    const float* __restrict__ Whh, const float* __restrict__ bhh,
    const float* __restrict__ Wq1, const float* __restrict__ bq1,
    const float* __restrict__ Wq2, const float* __restrict__ bq2,
    const float* __restrict__ v,   const float* __restrict__ Wh,
    const float* __restrict__ bh,  const int* __restrict__ start_nodes,
    float* __restrict__ tours_o, float* __restrict__ lp_o)
{
  __shared__ __align__(16) float keys_s[128*KSTRIDE];  // 132 KB, transposed E-keys
  __shared__ __align__(16) float h_s[2][160];          // staggered (H2A)
  __shared__ __align__(16) float qh_s[160];            // staggered (H2A)
  __shared__ __align__(16) float q_s[160];             // PAD16 (raw q), also gctx scratch
  __shared__ __align__(16) float v_sp[160];            // PAD16 layout, -2*v
  __shared__ __align__(16) float spartS[8*SSTR];       // score partials (+init scratch)
  __shared__ int col2node_s[256];
  __shared__ float red2[8];

  const int t = threadIdx.x;
  const int b = blockIdx.x;
  const int g  = t >> 2, s3 = t & 3;   // 128 groups x 4 lanes (matvec)
  const int w  = t >> 6, L  = t & 63;
  const int oct = L & 7, dgrp = L >> 3; // score: col-octet, dim-group

  // register weights: Whh rows g,128+g,256+g (chunk s3*32); Wq1/Wq2 row g
  float4 whh4[3][8], wq14[8], wq24[8];
  {
    const float4* w0  = (const float4*)(Whh + (size_t)(g      )*128 + s3*32);
    const float4* w1  = (const float4*)(Whh + (size_t)(128 + g)*128 + s3*32);
    const float4* w2  = (const float4*)(Whh + (size_t)(256 + g)*128 + s3*32);
    const float4* q1p = (const float4*)(Wq1 + (size_t)g*128 + s3*32);
    const float4* q2p = (const float4*)(Wq2 + (size_t)g*128 + s3*32);
    #pragma unroll
    for (int i=0;i<8;i++){
      whh4[0][i]=w0[i]; whh4[1][i]=w1[i]; whh4[2][i]=w2[i];
      wq14[i]=q1p[i];   wq24[i]=q2p[i];
    }
  }
  const float br = bhh[g], bz = bhh[128+g], bn = bhh[256+g];
  const float b1g = bq1[g], b2g = bq2[g];

  if (t<128) v_sp[PAD16(t)] = -2.f * v[t];
  if (t<256) col2node_s[t] = t;
  { // stage transposed E-keys: coalesced per d-row
    #pragma unroll
    for (int m=0;m<16;m++){
      int idx = m*512 + t; int d = idx>>6, q = idx&63;
      *(float4*)(keys_s + d*KSTRIDE + q*4) =
        *(const float4*)(keysE + (size_t)d*TTOT + b*256 + q*4);
    }
  }
  { // graph-context partial sums (4 parts x 64 nodes)
    int d = t & 127, part = t >> 7;
    float a = 0.f;
    const float* base = emb + (size_t)(b*256 + part*64)*128 + d;
    for (int i=0;i<64;i++) a += base[(size_t)i*128];
    spartS[part*128+d] = a;
  }
  int cur = start_nodes[b];
  // px_cur = column of cur in the compacted keys layout. Maps start as
  // identity, so at step 0 px_cur = local node id; thereafter px_cur = besti
  // (bijection invariant: node chosen FROM column besti sits AT column besti).
  int px_cur = cur - b*256;
  __syncthreads();
  if (t<128){
    float a = 0.f;
    #pragma unroll
    for (int p=0;p<4;p++) a += spartS[p*128+t];
    q_s[t] = a * (1.f/256.f);          // gctx temp (plain idx, init only)
  }
  __syncthreads();
  if (t<128){ // hidden0 = gctx@Wh.T + bh  (write staggered)
    float a = bh[t];
    const float* wr = Wh + (size_t)t*128;
    for (int k=0;k<128;k++) a += wr[k]*q_s[k];
    h_s[0][H2A(t)] = a;
  }
  { // sv = sum(v)
    float xv = (t<128) ? v[t] : 0.f;
    float tot = dpp_wave_sum(xv);
    if (L==0) red2[w] = tot;
  }
  __syncthreads();
  float sv = 0.f;
  #pragma unroll
  for (int i=0;i<8;i++) sv += red2[i];

  // gi prefetch for step 0
  float gir=0.f, giz=0.f, gin=0.f;
  if (s3==0){
    const float* gp = giall + (size_t)cur*384 + g;
    gir = gp[0]; giz = gp[128]; gin = gp[256];
  }

  for (int step=0; step<255; step++){
    const int par = step & 1;
    const int V   = 255 - step;          // valid count after removing cur

    // ---- swap-remove cur's keys column (waves 2-3; px_cur in register:
    //      no map lookups on this chain anymore) ----
    if (t >= 128 && t < 256){
      int r = t - 128;
      keys_s[r*KSTRIDE + px_cur] = keys_s[r*KSTRIDE + V];
    }
    if (t == 384) tours_o[b*256+step] = (float)cur;   // wave 6

    // ---- phase A: gh dots + fused GRU -> h_s[par^1] ----
    {
      float a0=0.f,a1=0.f,a2=0.f;
      const float4* hc4 = (const float4*)(h_s[par] + s3*40);
      #pragma unroll
      for (int i=0;i<8;i++){
        float4 hv = hc4[i];
        a0 += dot4(whh4[0][i], hv);
        a1 += dot4(whh4[1][i], hv);
        a2 += dot4(whh4[2][i], hv);
      }
      a0 = quad_sum_dpp(a0);
      a1 = quad_sum_dpp(a1);
      a2 = quad_sum_dpp(a2);
      if (s3==0){
        float r = sigfast(gir + a0 + br);
        float z = sigfast(giz + a1 + bz);
        float n = tanhfast(gin + r*(a2 + bn));
        h_s[par^1][H2A(g)] = (1.f-z)*n + z*h_s[par][H2A(g)];
      }
    }
    __syncthreads();                                   // B1

    // ---- deferred index-map update (wave 7; race-free: all prev-step
    //      combine reads of col2node_s completed before B1). Single lookup:
    //      col2node_s[px_cur] = col2node_s[V]; node2col map no longer exists. ----
    if (t == 448){
      col2node_s[px_cur] = col2node_s[V];
    }

    { // qh = relu(h@Wq1.T + bq1)
      float a=0.f;
      const float4* hc4 = (const float4*)(h_s[par^1] + s3*40);
      #pragma unroll
      for (int i=0;i<8;i++) a += dot4(wq14[i], hc4[i]);
      a = quad_sum_dpp(a);
      if (s3==0) qh_s[H2A(g)] = fmaxf(a + b1g, 0.f);
    }
    __syncthreads();                                   // B2

    { // q_raw = qh@Wq2.T + bq2 (PAD16 store) ; per-wave ssq via DPP
      float a=0.f;
      const float4* qc4 = (const float4*)(qh_s + s3*40);
      #pragma unroll
      for (int i=0;i<8;i++) a += dot4(wq24[i], qc4[i]);
      a = quad_sum_dpp(a);
      float qval = a + b2g;
      if (s3==0) q_s[PAD16(g)] = qval;
      float ssp = (s3==0) ? qval*qval : 0.f;
      float tot = dpp_wave_sum(ssp);
      if (L==0) red2[w] = tot;
    }
    __syncthreads();                                   // B3

    // ---- score: wave w -> cols 32w..32w+31 (whole-wave skip when 32w >= V);
    //      rn/eq computed inline ----
    if (32*w < V){
      float ss = 0.f;
      #pragma unroll
      for (int i=0;i<8;i++) ss += red2[i];
      float rn = 1.f / fmaxf(sqrtf(ss), 1e-12f);
      const float* kbase = keys_s + dgrp*16*KSTRIDE + 32*w + oct*4;
      const float* qb    = q_s  + dgrp*20;
      const float* vbase = v_sp + dgrp*20;
      float4 acc = {0.f,0.f,0.f,0.f};
      #pragma unroll
      for (int jj=0;jj<16;jj++){
        float eqj = __builtin_amdgcn_exp2f(qb[jj] * rn * LOG2E2);
        float vj  = vbase[jj];
        float4 K = *(const float4*)(kbase + jj*KSTRIDE);
        float r0 = __builtin_amdgcn_rcpf(fmaf(K.x, eqj, 1.f));
        float r1 = __builtin_amdgcn_rcpf(fmaf(K.y, eqj, 1.f));
        float r2 = __builtin_amdgcn_rcpf(fmaf(K.z, eqj, 1.f));
        float r3 = __builtin_amdgcn_rcpf(fmaf(K.w, eqj, 1.f));
        acc.x = fmaf(vj, r0, acc.x);
        acc.y = fmaf(vj, r1, acc.y);
        acc.z = fmaf(vj, r2, acc.z);
        acc.w = fmaf(vj, r3, acc.w);
      }
      *(float4*)(spartS + dgrp*SSTR + 32*w + oct*4) = acc;
    }
    __syncthreads();                                   // Bs1

    // ---- redundant combine: EVERY wave reduces all 256 cols; every lane
    //      learns argmax -> no Bs2, no tail round-trip. es/S/lp: wave 5 only. ----
    {
      const float* sp = spartS + 4*L;
      float sx=0.f, sy=0.f, sz=0.f, sw=0.f;
      #pragma unroll
      for (int i=0;i<8;i++){
        float4 p = *(const float4*)(sp + i*SSTR);
        sx += p.x; sy += p.y; sz += p.z; sw += p.w;
      }
      int c0 = 4*L;
      float vx = (c0+0 < V) ? sv+sx : -INFINITY;
      float vy = (c0+1 < V) ? sv+sy : -INFINITY;
      float vz = (c0+2 < V) ? sv+sz : -INFINITY;
      float vw = (c0+3 < V) ? sv+sw : -INFINITY;
      float bm = vx; int bc = c0;                 // first-max tie-break
      if (vy > bm){ bm=vy; bc=c0+1; }
      if (vz > bm){ bm=vz; bc=c0+2; }
      if (vw > bm){ bm=vw; bc=c0+3; }
      float m = dpp_wave_max(bm);
      unsigned long long mk = __ballot(bm == m);
      int flane = __ffsll(mk) - 1;                // lowest lane = lowest col
      int besti = __builtin_amdgcn_readlane(bc, flane);
      cur = b*256 + col2node_s[besti];            // read pre-next-update map
      if (s3==0){   // prefetch next gi (consumed in next phase A)
        const float* gp = giall + (size_t)cur*384 + g;
        gir = gp[0]; giz = gp[128]; gin = gp[256];
      }
      if (w == 5){  // softmax tail on wave 5 only (was redundant on all waves)
        float es = __builtin_amdgcn_exp2f((vx-m)*LOG2E) + __builtin_amdgcn_exp2f((vy-m)*LOG2E)
                 + __builtin_amdgcn_exp2f((vz-m)*LOG2E) + __builtin_amdgcn_exp2f((vw-m)*LOG2E);
        float S = dpp_wave_sum(es);
        if (L==0) lp_o[b*255+step] = logf(1.f/S + 1e-10f);
      }
      px_cur = besti;   // wave-uniform; next step's swap column == besti
    }
    // no barrier: next step's keys-swap/phase-A touch no combine-read state
  }
  if (t==0) tours_o[b*256+255] = (float)cur;

  (void)oct;
}

extern "C" void kernel_launch(void* const* d_in, const int* in_sizes, int n_in,
                              void* d_out, int out_size, void* d_ws, size_t ws_size,
                              hipStream_t stream) {
  const float* emb  = (const float*)d_in[0];
  const int*   startn = (const int*)d_in[1];
  const float* Wq1 = (const float*)d_in[3];  const float* bq1 = (const float*)d_in[4];
  const float* Wq2 = (const float*)d_in[5];  const float* bq2 = (const float*)d_in[6];
  const float* Wk1 = (const float*)d_in[7];  const float* bk1 = (const float*)d_in[8];
  const float* Wk2 = (const float*)d_in[9];  const float* bk2 = (const float*)d_in[10];
  const float* Wih = (const float*)d_in[11]; const float* Whh = (const float*)d_in[12];
  const float* bih = (const float*)d_in[13]; const float* bhh = (const float*)d_in[14];
  const float* v   = (const float*)d_in[15]; const float* Wh  = (const float*)d_in[16];
  const float* bh  = (const float*)d_in[17];

  float* keysE = (float*)d_ws;               // exp(2*keys) TRANSPOSED [128][8192]
  float* giall = keysE + (size_t)TTOT*DD;    // [8192*384]

  float* outp = (float*)d_out;   // tours [32*256] then log_probs [32*255]

  precompute_kernel<<<256, 256, 0, stream>>>(emb, Wk1, bk1, Wk2, bk2, Wih, bih, keysE, giall);
  decode_kernel<<<NGR, 512, 0, stream>>>(emb, keysE, giall, Whh, bhh, Wq1, bq1, Wq2, bq2,
                                         v, Wh, bh, startn, outp, outp + TTOT);
}

// Round 6
// 890.399 us; speedup vs baseline: 2.5656x; 1.0370x over previous
//
#include <hip/hip_runtime.h>
#include <hip/hip_bf16.h>
#include <math.h>

// B=32 graphs, N=256 nodes/graph, D=128.
#define DD   128
#define NPG  256
#define NGR  32
#define TTOT 8192
#define LOG2E  1.4426950408889634f
#define LOG2E2 2.8853900817779268f   // 2*log2(e)
#define KSTRIDE 264                   // LDS floats per transposed key row
#define SSTR    268                   // spartS row stride
#define H2A(j)  ((j) + (((j)>>5)<<3))   // stagger: chunk base -> bank chunk*8
#define PAD16(j) ((j) + (((j)>>4)<<2))  // q/v pad: d -> d + (d>>4)*4

__device__ __forceinline__ float dot4(float4 a, float4 b){
  return a.x*b.x + a.y*b.y + a.z*b.z + a.w*b.w;
}
// ---- DPP cross-lane (VALU pipe; keeps ds_bpermute off critical chains) ----
template<int CTRL, int RMASK>
__device__ __forceinline__ float upd_f(float oldv, float x){
  return __int_as_float(__builtin_amdgcn_update_dpp(
      __float_as_int(oldv), __float_as_int(x), CTRL, RMASK, 0xf, false));
}
__device__ __forceinline__ float dpp_xor1(float x){
  return __int_as_float(__builtin_amdgcn_mov_dpp(__float_as_int(x), 0xB1, 0xf, 0xf, false));
}
__device__ __forceinline__ float dpp_xor2(float x){
  return __int_as_float(__builtin_amdgcn_mov_dpp(__float_as_int(x), 0x4E, 0xf, 0xf, false));
}
__device__ __forceinline__ float quad_sum_dpp(float x){
  float s = x + dpp_xor1(x);
  return s + dpp_xor2(s);
}
__device__ __forceinline__ float dpp_wave_sum(float x){
  x += upd_f<0x111,0xf>(0.f, x);   // row_shr:1
  x += upd_f<0x112,0xf>(0.f, x);   // row_shr:2
  x += upd_f<0x114,0xf>(0.f, x);   // row_shr:4
  x += upd_f<0x118,0xf>(0.f, x);   // row_shr:8
  x += upd_f<0x142,0xa>(0.f, x);   // row_bcast15
  x += upd_f<0x143,0xc>(0.f, x);   // row_bcast31
  return __uint_as_float(__builtin_amdgcn_readlane(__float_as_uint(x), 63));
}
__device__ __forceinline__ float dpp_wave_max(float x){
  const float NI = -INFINITY;
  x = fmaxf(x, upd_f<0x111,0xf>(NI, x));
  x = fmaxf(x, upd_f<0x112,0xf>(NI, x));
  x = fmaxf(x, upd_f<0x114,0xf>(NI, x));
  x = fmaxf(x, upd_f<0x118,0xf>(NI, x));
  x = fmaxf(x, upd_f<0x142,0xa>(NI, x));
  x = fmaxf(x, upd_f<0x143,0xc>(NI, x));
  return __uint_as_float(__builtin_amdgcn_readlane(__float_as_uint(x), 63));
}
__device__ __forceinline__ float sigfast(float x){
  return __builtin_amdgcn_rcpf(1.f + __builtin_amdgcn_exp2f(-x*LOG2E));
}
__device__ __forceinline__ float tanhfast(float y){
  return 1.f - 2.f*__builtin_amdgcn_rcpf(1.f + __builtin_amdgcn_exp2f(y*LOG2E2));
}

// ---------------- Kernel 1: parallel precompute (R9/R12 SCALAR version) ----------------
// SCALAR mm_tile accumulation order is part of the validated-numerics contract
// (R10's float4 reorder flipped a near-tie argmax -> tour divergence). DO NOT vectorize.
// keysE[d][n] = exp(2 * l2norm(relu(emb@Wk1.T+bk1)@Wk2.T+bk2)[n][d])  [128][8192] TRANSPOSED
// gi_all = emb@W_ih.T + b_ih                                          [8192,384]

__device__ __forceinline__ void load_w128(float* Ws, const float* __restrict__ W, int t){
  const float4* src = (const float4*)W;
  #pragma unroll
  for (int m=0;m<16;m++){
    int idx = m*256+t; int r = idx>>5, c4 = idx&31;
    float4 val = src[idx];
    float* dst = &Ws[r*129 + c4*4];
    dst[0]=val.x; dst[1]=val.y; dst[2]=val.z; dst[3]=val.w;
  }
}

__device__ __forceinline__ void mm_tile(const float* __restrict__ inS, const float* __restrict__ Ws,
                                        float acc[4][4], int jg, int ng){
  #pragma unroll
  for(int r=0;r<4;r++)
    #pragma unroll
    for(int c=0;c<4;c++) acc[r][c]=0.f;
  #pragma unroll 4
  for (int k=0;k<128;k++){
    float w[4], x[4];
    #pragma unroll
    for (int r=0;r<4;r++) w[r] = Ws[(jg*4+r)*129+k];
    #pragma unroll
    for (int c=0;c<4;c++) x[c] = inS[(ng*4+c)*129+k];
    #pragma unroll
    for (int r=0;r<4;r++)
      #pragma unroll
      for (int c=0;c<4;c++) acc[r][c] += w[r]*x[c];
  }
}

__global__ __launch_bounds__(256) void precompute_kernel(
    const float* __restrict__ emb,
    const float* __restrict__ Wk1, const float* __restrict__ bk1,
    const float* __restrict__ Wk2, const float* __restrict__ bk2,
    const float* __restrict__ Wih, const float* __restrict__ bih,
    float* __restrict__ keysE, float* __restrict__ giall)
{
  __shared__ __align__(16) float xs[32*129];
  __shared__ __align__(16) float Ws[128*129];
  __shared__ __align__(16) float hs[32*129];
  __shared__ __align__(16) float os[32*129];
  __shared__ float nrm[32];
  const int t  = threadIdx.x;
  const int n0 = blockIdx.x * 32;
  const int ng = t & 7, jg = t >> 3;

  {
    const float4* src = (const float4*)emb + (size_t)n0*32;
    #pragma unroll
    for (int m=0;m<4;m++){
      int idx = m*256+t; int n = idx>>5, c4 = idx&31;
      float4 val = src[idx];
      float* dst = &xs[n*129 + c4*4];
      dst[0]=val.x; dst[1]=val.y; dst[2]=val.z; dst[3]=val.w;
    }
  }
  load_w128(Ws, Wk1, t);
  __syncthreads();
  {
    float acc[4][4];
    mm_tile(xs, Ws, acc, jg, ng);
    #pragma unroll
    for (int r=0;r<4;r++){
      float bb = bk1[jg*4+r];
      #pragma unroll
      for (int c=0;c<4;c++) hs[(ng*4+c)*129 + jg*4+r] = fmaxf(acc[r][c]+bb, 0.f);
    }
  }
  __syncthreads();
  load_w128(Ws, Wk2, t);
  __syncthreads();
  {
    float acc[4][4];
    mm_tile(hs, Ws, acc, jg, ng);
    #pragma unroll
    for (int r=0;r<4;r++){
      float bb = bk2[jg*4+r];
      #pragma unroll
      for (int c=0;c<4;c++) os[(ng*4+c)*129 + jg*4+r] = acc[r][c]+bb;
    }
  }
  __syncthreads();
  if (t<32){
    float ss=0.f;
    for (int j=0;j<128;j++){ float x = os[t*129+j]; ss += x*x; }
    nrm[t] = fmaxf(sqrtf(ss), 1e-12f);
  }
  __syncthreads();
  // transposed E-keys: keysE[d][n] = exp(2*K)
  #pragma unroll
  for (int m=0;m<16;m++){
    int idx = m*256+t; int nl = idx & 31, d = idx >> 5;
    float kk = os[nl*129 + d] / nrm[nl];
    keysE[(size_t)d*TTOT + n0 + nl] = __builtin_amdgcn_exp2f(kk * LOG2E2);
  }
  for (int c=0;c<3;c++){
    __syncthreads();
    load_w128(Ws, Wih + c*16384, t);
    __syncthreads();
    float acc[4][4];
    mm_tile(xs, Ws, acc, jg, ng);
    #pragma unroll
    for (int r=0;r<4;r++){
      float bb = bih[c*128 + jg*4+r];
      #pragma unroll
      for (int cc=0;cc<4;cc++)
        giall[(size_t)(n0 + ng*4+cc)*384 + c*128 + jg*4 + r] = acc[r][cc] + bb;
    }
  }
}

// ---------------- Kernel 2: sequential decode ----------------
// R18 = ISOLATION ROUND: exact R12 structure + ONLY change (b) from R17:
//   px == besti identity. The swap's old px = node2col[col2node[besti]] is
//   the identity (inverse bijections, same map state at read time). px_cur is
//   carried in a wave-uniform SGPR (zero VGPR cost); node2col_s is deleted;
//   the t==448 update shrinks to col2node_s[px_cur] = col2node_s[V].
// The combine tail is byte-for-byte R12: ALL waves compute es/S in the same
// order (es -> S -> cur -> prefetch -> lp by t==320). R17 bundled (a) the
// wave5-only tail with (b); R17 regressed +45us with LESS VALU work, so one
// of the two adds stall. This round separates them.
// Pre-committed: <=765 -> (a) was the regression, keep (b). ~810 -> (b) is
// the regression -> full R12 revert next round and settle.
// Hard constraints (R13/R14/R16): 512 threads, lb(512,2), no new persistent
// per-LANE registers (128-VGPR spill cliff).

__global__ __launch_bounds__(512, 2) void decode_kernel(
    const float* __restrict__ emb,
    const float* __restrict__ keysE, const float* __restrict__ giall,
    const float* __restrict__ Whh, const float* __restrict__ bhh,
    const float* __restrict__ Wq1, const float* __restrict__ bq1,
    const float* __restrict__ Wq2, const float* __restrict__ bq2,
    const float* __restrict__ v,   const float* __restrict__ Wh,
    const float* __restrict__ bh,  const int* __restrict__ start_nodes,
    float* __restrict__ tours_o, float* __restrict__ lp_o)
{
  __shared__ __align__(16) float keys_s[128*KSTRIDE];  // 132 KB, transposed E-keys
  __shared__ __align__(16) float h_s[2][160];          // staggered (H2A)
  __shared__ __align__(16) float qh_s[160];            // staggered (H2A)
  __shared__ __align__(16) float q_s[160];             // PAD16 (raw q), also gctx scratch
  __shared__ __align__(16) float v_sp[160];            // PAD16 layout, -2*v
  __shared__ __align__(16) float spartS[8*SSTR];       // score partials (+init scratch)
  __shared__ int col2node_s[256];
  __shared__ float red2[8];

  const int t = threadIdx.x;
  const int b = blockIdx.x;
  const int g  = t >> 2, s3 = t & 3;   // 128 groups x 4 lanes (matvec)
  const int w  = t >> 6, L  = t & 63;
  const int oct = L & 7, dgrp = L >> 3; // score: col-octet, dim-group

  // register weights: Whh rows g,128+g,256+g (chunk s3*32); Wq1/Wq2 row g
  float4 whh4[3][8], wq14[8], wq24[8];
  {
    const float4* w0  = (const float4*)(Whh + (size_t)(g      )*128 + s3*32);
    const float4* w1  = (const float4*)(Whh + (size_t)(128 + g)*128 + s3*32);
    const float4* w2  = (const float4*)(Whh + (size_t)(256 + g)*128 + s3*32);
    const float4* q1p = (const float4*)(Wq1 + (size_t)g*128 + s3*32);
    const float4* q2p = (const float4*)(Wq2 + (size_t)g*128 + s3*32);
    #pragma unroll
    for (int i=0;i<8;i++){
      whh4[0][i]=w0[i]; whh4[1][i]=w1[i]; whh4[2][i]=w2[i];
      wq14[i]=q1p[i];   wq24[i]=q2p[i];
    }
  }
  const float br = bhh[g], bz = bhh[128+g], bn = bhh[256+g];
  const float b1g = bq1[g], b2g = bq2[g];

  if (t<128) v_sp[PAD16(t)] = -2.f * v[t];
  if (t<256) col2node_s[t] = t;
  { // stage transposed E-keys: coalesced per d-row
    #pragma unroll
    for (int m=0;m<16;m++){
      int idx = m*512 + t; int d = idx>>6, q = idx&63;
      *(float4*)(keys_s + d*KSTRIDE + q*4) =
        *(const float4*)(keysE + (size_t)d*TTOT + b*256 + q*4);
    }
  }
  { // graph-context partial sums (4 parts x 64 nodes)
    int d = t & 127, part = t >> 7;
    float a = 0.f;
    const float* base = emb + (size_t)(b*256 + part*64)*128 + d;
    for (int i=0;i<64;i++) a += base[(size_t)i*128];
    spartS[part*128+d] = a;
  }
  int cur = start_nodes[b];
  // px_cur = column of cur in the compacted keys layout. Identity map at
  // step 0, thereafter px_cur = besti (bijection invariant).
  int px_cur = cur - b*256;
  __syncthreads();
  if (t<128){
    float a = 0.f;
    #pragma unroll
    for (int p=0;p<4;p++) a += spartS[p*128+t];
    q_s[t] = a * (1.f/256.f);          // gctx temp (plain idx, init only)
  }
  __syncthreads();
  if (t<128){ // hidden0 = gctx@Wh.T + bh  (write staggered)
    float a = bh[t];
    const float* wr = Wh + (size_t)t*128;
    for (int k=0;k<128;k++) a += wr[k]*q_s[k];
    h_s[0][H2A(t)] = a;
  }
  { // sv = sum(v)
    float xv = (t<128) ? v[t] : 0.f;
    float tot = dpp_wave_sum(xv);
    if (L==0) red2[w] = tot;
  }
  __syncthreads();
  float sv = 0.f;
  #pragma unroll
  for (int i=0;i<8;i++) sv += red2[i];

  // gi prefetch for step 0
  float gir=0.f, giz=0.f, gin=0.f;
  if (s3==0){
    const float* gp = giall + (size_t)cur*384 + g;
    gir = gp[0]; giz = gp[128]; gin = gp[256];
  }

  for (int step=0; step<255; step++){
    const int par = step & 1;
    const int V   = 255 - step;          // valid count after removing cur

    // ---- swap-remove cur's keys column (waves 2-3; px_cur in register:
    //      the old node2col lookup was the identity -> deleted) ----
    if (t >= 128 && t < 256){
      int r = t - 128;
      keys_s[r*KSTRIDE + px_cur] = keys_s[r*KSTRIDE + V];
    }
    if (t == 384) tours_o[b*256+step] = (float)cur;   // wave 6

    // ---- phase A: gh dots + fused GRU -> h_s[par^1] ----
    {
      float a0=0.f,a1=0.f,a2=0.f;
      const float4* hc4 = (const float4*)(h_s[par] + s3*40);
      #pragma unroll
      for (int i=0;i<8;i++){
        float4 hv = hc4[i];
        a0 += dot4(whh4[0][i], hv);
        a1 += dot4(whh4[1][i], hv);
        a2 += dot4(whh4[2][i], hv);
      }
      a0 = quad_sum_dpp(a0);
      a1 = quad_sum_dpp(a1);
      a2 = quad_sum_dpp(a2);
      if (s3==0){
        float r = sigfast(gir + a0 + br);
        float z = sigfast(giz + a1 + bz);
        float n = tanhfast(gin + r*(a2 + bn));
        h_s[par^1][H2A(g)] = (1.f-z)*n + z*h_s[par][H2A(g)];
      }
    }
    __syncthreads();                                   // B1

    // ---- deferred index-map update (wave 7; race-free: all prev-step
    //      combine reads of col2node_s completed before B1). Single lookup. ----
    if (t == 448){
      col2node_s[px_cur] = col2node_s[V];
    }

    { // qh = relu(h@Wq1.T + bq1)
      float a=0.f;
      const float4* hc4 = (const float4*)(h_s[par^1] + s3*40);
      #pragma unroll
      for (int i=0;i<8;i++) a += dot4(wq14[i], hc4[i]);
      a = quad_sum_dpp(a);
      if (s3==0) qh_s[H2A(g)] = fmaxf(a + b1g, 0.f);
    }
    __syncthreads();                                   // B2

    { // q_raw = qh@Wq2.T + bq2 (PAD16 store) ; per-wave ssq via DPP
      float a=0.f;
      const float4* qc4 = (const float4*)(qh_s + s3*40);
      #pragma unroll
      for (int i=0;i<8;i++) a += dot4(wq24[i], qc4[i]);
      a = quad_sum_dpp(a);
      float qval = a + b2g;
      if (s3==0) q_s[PAD16(g)] = qval;
      float ssp = (s3==0) ? qval*qval : 0.f;
      float tot = dpp_wave_sum(ssp);
      if (L==0) red2[w] = tot;
    }
    __syncthreads();                                   // B3

    // ---- score: wave w -> cols 32w..32w+31 (whole-wave skip when 32w >= V);
    //      rn/eq computed inline ----
    if (32*w < V){
      float ss = 0.f;
      #pragma unroll
      for (int i=0;i<8;i++) ss += red2[i];
      float rn = 1.f / fmaxf(sqrtf(ss), 1e-12f);
      const float* kbase = keys_s + dgrp*16*KSTRIDE + 32*w + oct*4;
      const float* qb    = q_s  + dgrp*20;
      const float* vbase = v_sp + dgrp*20;
      float4 acc = {0.f,0.f,0.f,0.f};
      #pragma unroll
      for (int jj=0;jj<16;jj++){
        float eqj = __builtin_amdgcn_exp2f(qb[jj] * rn * LOG2E2);
        float vj  = vbase[jj];
        float4 K = *(const float4*)(kbase + jj*KSTRIDE);
        float r0 = __builtin_amdgcn_rcpf(fmaf(K.x, eqj, 1.f));
        float r1 = __builtin_amdgcn_rcpf(fmaf(K.y, eqj, 1.f));
        float r2 = __builtin_amdgcn_rcpf(fmaf(K.z, eqj, 1.f));
        float r3 = __builtin_amdgcn_rcpf(fmaf(K.w, eqj, 1.f));
        acc.x = fmaf(vj, r0, acc.x);
        acc.y = fmaf(vj, r1, acc.y);
        acc.z = fmaf(vj, r2, acc.z);
        acc.w = fmaf(vj, r3, acc.w);
      }
      *(float4*)(spartS + dgrp*SSTR + 32*w + oct*4) = acc;
    }
    __syncthreads();                                   // Bs1

    // ---- redundant combine: EVERY wave reduces all 256 cols; every lane
    //      learns argmax + softmax sum -> no Bs2, no tail round-trip.
    //      (exact R12 tail: es/S on ALL waves, then cur, prefetch, lp.) ----
    {
      const float* sp = spartS + 4*L;
      float sx=0.f, sy=0.f, sz=0.f, sw=0.f;
      #pragma unroll
      for (int i=0;i<8;i++){
        float4 p = *(const float4*)(sp + i*SSTR);
        sx += p.x; sy += p.y; sz += p.z; sw += p.w;
      }
      int c0 = 4*L;
      float vx = (c0+0 < V) ? sv+sx : -INFINITY;
      float vy = (c0+1 < V) ? sv+sy : -INFINITY;
      float vz = (c0+2 < V) ? sv+sz : -INFINITY;
      float vw = (c0+3 < V) ? sv+sw : -INFINITY;
      float bm = vx; int bc = c0;                 // first-max tie-break
      if (vy > bm){ bm=vy; bc=c0+1; }
      if (vz > bm){ bm=vz; bc=c0+2; }
      if (vw > bm){ bm=vw; bc=c0+3; }
      float m = dpp_wave_max(bm);
      unsigned long long mk = __ballot(bm == m);
      int flane = __ffsll(mk) - 1;                // lowest lane = lowest col
      int besti = __builtin_amdgcn_readlane(bc, flane);
      float es = __builtin_amdgcn_exp2f((vx-m)*LOG2E) + __builtin_amdgcn_exp2f((vy-m)*LOG2E)
               + __builtin_amdgcn_exp2f((vz-m)*LOG2E) + __builtin_amdgcn_exp2f((vw-m)*LOG2E);
      float S = dpp_wave_sum(es);
      cur = b*256 + col2node_s[besti];            // read pre-next-update map
      if (s3==0){   // prefetch next gi (consumed in next phase A)
        const float* gp = giall + (size_t)cur*384 + g;
        gir = gp[0]; giz = gp[128]; gin = gp[256];
      }
      if (t==320) lp_o[b*255+step] = logf(1.f/S + 1e-10f);  // wave 5
      px_cur = besti;   // wave-uniform; next step's swap column == besti
    }
    // no barrier: next step's keys-swap/phase-A touch no combine-read state
  }
  if (t==0) tours_o[b*256+255] = (float)cur;

  (void)oct; (void)dgrp;
}

extern "C" void kernel_launch(void* const* d_in, const int* in_sizes, int n_in,
                              void* d_out, int out_size, void* d_ws, size_t ws_size,
                              hipStream_t stream) {
  const float* emb  = (const float*)d_in[0];
  const int*   startn = (const int*)d_in[1];
  const float* Wq1 = (const float*)d_in[3];  const float* bq1 = (const float*)d_in[4];
  const float* Wq2 = (const float*)d_in[5];  const float* bq2 = (const float*)d_in[6];
  const float* Wk1 = (const float*)d_in[7];  const float* bk1 = (const float*)d_in[8];
  const float* Wk2 = (const float*)d_in[9];  const float* bk2 = (const float*)d_in[10];
  const float* Wih = (const float*)d_in[11]; const float* Whh = (const float*)d_in[12];
  const float* bih = (const float*)d_in[13]; const float* bhh = (const float*)d_in[14];
  const float* v   = (const float*)d_in[15]; const float* Wh  = (const float*)d_in[16];
  const float* bh  = (const float*)d_in[17];

  float* keysE = (float*)d_ws;               // exp(2*keys) TRANSPOSED [128][8192]
  float* giall = keysE + (size_t)TTOT*DD;    // [8192*384]

  float* outp = (float*)d_out;   // tours [32*256] then log_probs [32*255]

  precompute_kernel<<<256, 256, 0, stream>>>(emb, Wk1, bk1, Wk2, bk2, Wih, bih, keysE, giall);
  decode_kernel<<<NGR, 512, 0, stream>>>(emb, keysE, giall, Whh, bhh, Wq1, bq1, Wq2, bq2,
                                         v, Wh, bh, startn, outp, outp + TTOT);
}

// Round 7
// 886.028 us; speedup vs baseline: 2.5783x; 1.0049x over previous
//
#include <hip/hip_runtime.h>
#include <hip/hip_bf16.h>
#include <math.h>

// B=32 graphs, N=256 nodes/graph, D=128.
#define DD   128
#define NPG  256
#define NGR  32
#define TTOT 8192
#define LOG2E  1.4426950408889634f
#define LOG2E2 2.8853900817779268f   // 2*log2(e)
#define KSTRIDE 264                   // LDS floats per transposed key row
#define SSTR    268                   // spartS row stride
#define H2A(j)  ((j) + (((j)>>5)<<3))   // stagger: chunk base -> bank chunk*8
#define PAD16(j) ((j) + (((j)>>4)<<2))  // q/v pad: d -> d + (d>>4)*4

// R19 = terminal restore of the best-measured kernel (R12, 765us decode /
// 886us total). Session isolation ledger (all single-change A/B vs R12):
//   giall L2-warm:                 0   (R15)
//   per-thread map registers:   +135   (R14; spill at 128-VGPR cliff)
//   9th service wave (576 thr): +1400  (R16; spill)
//   wave5-only softmax tail:     +38   (R17-R18)
//   px==besti LDS-read removal:   +7   (R18; neutral/noise)
// Conclusion: R12 is a phase-locked local floor. 7200 cy/step = phase chains
// (~2700) + 4 barrier drains + LDS latency un-hidden at 2 waves/SIMD.
// Hard constraints (measured): 512 threads, lb(512,2), zero new persistent
// per-lane registers, scalar accumulation orders (argmax tie contract).

__device__ __forceinline__ float dot4(float4 a, float4 b){
  return a.x*b.x + a.y*b.y + a.z*b.z + a.w*b.w;
}
// ---- DPP cross-lane (VALU pipe; keeps ds_bpermute off critical chains) ----
template<int CTRL, int RMASK>
__device__ __forceinline__ float upd_f(float oldv, float x){
  return __int_as_float(__builtin_amdgcn_update_dpp(
      __float_as_int(oldv), __float_as_int(x), CTRL, RMASK, 0xf, false));
}
__device__ __forceinline__ float dpp_xor1(float x){
  return __int_as_float(__builtin_amdgcn_mov_dpp(__float_as_int(x), 0xB1, 0xf, 0xf, false));
}
__device__ __forceinline__ float dpp_xor2(float x){
  return __int_as_float(__builtin_amdgcn_mov_dpp(__float_as_int(x), 0x4E, 0xf, 0xf, false));
}
__device__ __forceinline__ float quad_sum_dpp(float x){
  float s = x + dpp_xor1(x);
  return s + dpp_xor2(s);
}
__device__ __forceinline__ float dpp_wave_sum(float x){
  x += upd_f<0x111,0xf>(0.f, x);   // row_shr:1
  x += upd_f<0x112,0xf>(0.f, x);   // row_shr:2
  x += upd_f<0x114,0xf>(0.f, x);   // row_shr:4
  x += upd_f<0x118,0xf>(0.f, x);   // row_shr:8
  x += upd_f<0x142,0xa>(0.f, x);   // row_bcast15
  x += upd_f<0x143,0xc>(0.f, x);   // row_bcast31
  return __uint_as_float(__builtin_amdgcn_readlane(__float_as_uint(x), 63));
}
__device__ __forceinline__ float dpp_wave_max(float x){
  const float NI = -INFINITY;
  x = fmaxf(x, upd_f<0x111,0xf>(NI, x));
  x = fmaxf(x, upd_f<0x112,0xf>(NI, x));
  x = fmaxf(x, upd_f<0x114,0xf>(NI, x));
  x = fmaxf(x, upd_f<0x118,0xf>(NI, x));
  x = fmaxf(x, upd_f<0x142,0xa>(NI, x));
  x = fmaxf(x, upd_f<0x143,0xc>(NI, x));
  return __uint_as_float(__builtin_amdgcn_readlane(__float_as_uint(x), 63));
}
__device__ __forceinline__ float sigfast(float x){
  return __builtin_amdgcn_rcpf(1.f + __builtin_amdgcn_exp2f(-x*LOG2E));
}
__device__ __forceinline__ float tanhfast(float y){
  return 1.f - 2.f*__builtin_amdgcn_rcpf(1.f + __builtin_amdgcn_exp2f(y*LOG2E2));
}

// ---------------- Kernel 1: parallel precompute (R9/R12 SCALAR version) ----------------
// SCALAR mm_tile accumulation order is part of the validated-numerics contract
// (R10's float4 reorder flipped a near-tie argmax -> tour divergence). DO NOT vectorize.
// keysE[d][n] = exp(2 * l2norm(relu(emb@Wk1.T+bk1)@Wk2.T+bk2)[n][d])  [128][8192] TRANSPOSED
// gi_all = emb@W_ih.T + b_ih                                          [8192,384]

__device__ __forceinline__ void load_w128(float* Ws, const float* __restrict__ W, int t){
  const float4* src = (const float4*)W;
  #pragma unroll
  for (int m=0;m<16;m++){
    int idx = m*256+t; int r = idx>>5, c4 = idx&31;
    float4 val = src[idx];
    float* dst = &Ws[r*129 + c4*4];
    dst[0]=val.x; dst[1]=val.y; dst[2]=val.z; dst[3]=val.w;
  }
}

__device__ __forceinline__ void mm_tile(const float* __restrict__ inS, const float* __restrict__ Ws,
                                        float acc[4][4], int jg, int ng){
  #pragma unroll
  for(int r=0;r<4;r++)
    #pragma unroll
    for(int c=0;c<4;c++) acc[r][c]=0.f;
  #pragma unroll 4
  for (int k=0;k<128;k++){
    float w[4], x[4];
    #pragma unroll
    for (int r=0;r<4;r++) w[r] = Ws[(jg*4+r)*129+k];
    #pragma unroll
    for (int c=0;c<4;c++) x[c] = inS[(ng*4+c)*129+k];
    #pragma unroll
    for (int r=0;r<4;r++)
      #pragma unroll
      for (int c=0;c<4;c++) acc[r][c] += w[r]*x[c];
  }
}

__global__ __launch_bounds__(256) void precompute_kernel(
    const float* __restrict__ emb,
    const float* __restrict__ Wk1, const float* __restrict__ bk1,
    const float* __restrict__ Wk2, const float* __restrict__ bk2,
    const float* __restrict__ Wih, const float* __restrict__ bih,
    float* __restrict__ keysE, float* __restrict__ giall)
{
  __shared__ __align__(16) float xs[32*129];
  __shared__ __align__(16) float Ws[128*129];
  __shared__ __align__(16) float hs[32*129];
  __shared__ __align__(16) float os[32*129];
  __shared__ float nrm[32];
  const int t  = threadIdx.x;
  const int n0 = blockIdx.x * 32;
  const int ng = t & 7, jg = t >> 3;

  {
    const float4* src = (const float4*)emb + (size_t)n0*32;
    #pragma unroll
    for (int m=0;m<4;m++){
      int idx = m*256+t; int n = idx>>5, c4 = idx&31;
      float4 val = src[idx];
      float* dst = &xs[n*129 + c4*4];
      dst[0]=val.x; dst[1]=val.y; dst[2]=val.z; dst[3]=val.w;
    }
  }
  load_w128(Ws, Wk1, t);
  __syncthreads();
  {
    float acc[4][4];
    mm_tile(xs, Ws, acc, jg, ng);
    #pragma unroll
    for (int r=0;r<4;r++){
      float bb = bk1[jg*4+r];
      #pragma unroll
      for (int c=0;c<4;c++) hs[(ng*4+c)*129 + jg*4+r] = fmaxf(acc[r][c]+bb, 0.f);
    }
  }
  __syncthreads();
  load_w128(Ws, Wk2, t);
  __syncthreads();
  {
    float acc[4][4];
    mm_tile(hs, Ws, acc, jg, ng);
    #pragma unroll
    for (int r=0;r<4;r++){
      float bb = bk2[jg*4+r];
      #pragma unroll
      for (int c=0;c<4;c++) os[(ng*4+c)*129 + jg*4+r] = acc[r][c]+bb;
    }
  }
  __syncthreads();
  if (t<32){
    float ss=0.f;
    for (int j=0;j<128;j++){ float x = os[t*129+j]; ss += x*x; }
    nrm[t] = fmaxf(sqrtf(ss), 1e-12f);
  }
  __syncthreads();
  // transposed E-keys: keysE[d][n] = exp(2*K)
  #pragma unroll
  for (int m=0;m<16;m++){
    int idx = m*256+t; int nl = idx & 31, d = idx >> 5;
    float kk = os[nl*129 + d] / nrm[nl];
    keysE[(size_t)d*TTOT + n0 + nl] = __builtin_amdgcn_exp2f(kk * LOG2E2);
  }
  for (int c=0;c<3;c++){
    __syncthreads();
    load_w128(Ws, Wih + c*16384, t);
    __syncthreads();
    float acc[4][4];
    mm_tile(xs, Ws, acc, jg, ng);
    #pragma unroll
    for (int r=0;r<4;r++){
      float bb = bih[c*128 + jg*4+r];
      #pragma unroll
      for (int cc=0;cc<4;cc++)
        giall[(size_t)(n0 + ng*4+cc)*384 + c*128 + jg*4 + r] = acc[r][cc] + bb;
    }
  }
}

// ---------------- Kernel 2: sequential decode ----------------
// 32 blocks x 512 threads; 255 steps; FOUR barriers/step:
//  - B3b killed: score lanes compute rn/eq inline from q_s[PAD16]+red2.
//  - Bs2+tail killed: every wave redundantly reduces all 256 cols (float4
//    spartS reads, in-lane first-max, dpp max + ballot + readlane) -> every
//    lane knows argmax/softmax-sum without a barrier. Argmax inputs keep the
//    R12 summation order -> tours bit-identical; lp differs at ulp level.
//  - One-off jobs spread across waves (keys-swap: w2-3, tours: t==384,
//    map-update: t==448, lp: t==320) to cut barrier skew on wave 0.
// NOTE: the all-waves es/S tail is LOAD-BEARING (R17/R18 isolation: removing
// it from 7 waves costs +38us via phase-locking perturbation). Do not "optimize".

__global__ __launch_bounds__(512, 2) void decode_kernel(
    const float* __restrict__ emb,
    const float* __restrict__ keysE, const float* __restrict__ giall,
    const float* __restrict__ Whh, const float* __restrict__ bhh,
    const float* __restrict__ Wq1, const float* __restrict__ bq1,
    const float* __restrict__ Wq2, const float* __restrict__ bq2,
    const float* __restrict__ v,   const float* __restrict__ Wh,
    const float* __restrict__ bh,  const int* __restrict__ start_nodes,
    float* __restrict__ tours_o, float* __restrict__ lp_o)
{
  __shared__ __align__(16) float keys_s[128*KSTRIDE];  // 132 KB, transposed E-keys
  __shared__ __align__(16) float h_s[2][160];          // staggered (H2A)
  __shared__ __align__(16) float qh_s[160];            // staggered (H2A)
  __shared__ __align__(16) float q_s[160];             // PAD16 (raw q), also gctx scratch
  __shared__ __align__(16) float v_sp[160];            // PAD16 layout, -2*v
  __shared__ __align__(16) float spartS[8*SSTR];       // score partials (+init scratch)
  __shared__ int col2node_s[256], node2col_s[256];
  __shared__ float red2[8];

  const int t = threadIdx.x;
  const int b = blockIdx.x;
  const int g  = t >> 2, s3 = t & 3;   // 128 groups x 4 lanes (matvec)
  const int w  = t >> 6, L  = t & 63;
  const int oct = L & 7, dgrp = L >> 3; // score: col-octet, dim-group

  // register weights: Whh rows g,128+g,256+g (chunk s3*32); Wq1/Wq2 row g
  float4 whh4[3][8], wq14[8], wq24[8];
  {
    const float4* w0  = (const float4*)(Whh + (size_t)(g      )*128 + s3*32);
    const float4* w1  = (const float4*)(Whh + (size_t)(128 + g)*128 + s3*32);
    const float4* w2  = (const float4*)(Whh + (size_t)(256 + g)*128 + s3*32);
    const float4* q1p = (const float4*)(Wq1 + (size_t)g*128 + s3*32);
    const float4* q2p = (const float4*)(Wq2 + (size_t)g*128 + s3*32);
    #pragma unroll
    for (int i=0;i<8;i++){
      whh4[0][i]=w0[i]; whh4[1][i]=w1[i]; whh4[2][i]=w2[i];
      wq14[i]=q1p[i];   wq24[i]=q2p[i];
    }
  }
  const float br = bhh[g], bz = bhh[128+g], bn = bhh[256+g];
  const float b1g = bq1[g], b2g = bq2[g];

  if (t<128) v_sp[PAD16(t)] = -2.f * v[t];
  if (t<256){ col2node_s[t] = t; node2col_s[t] = t; }
  { // stage transposed E-keys: coalesced per d-row
    #pragma unroll
    for (int m=0;m<16;m++){
      int idx = m*512 + t; int d = idx>>6, q = idx&63;
      *(float4*)(keys_s + d*KSTRIDE + q*4) =
        *(const float4*)(keysE + (size_t)d*TTOT + b*256 + q*4);
    }
  }
  { // graph-context partial sums (4 parts x 64 nodes)
    int d = t & 127, part = t >> 7;
    float a = 0.f;
    const float* base = emb + (size_t)(b*256 + part*64)*128 + d;
    for (int i=0;i<64;i++) a += base[(size_t)i*128];
    spartS[part*128+d] = a;
  }
  int cur = start_nodes[b];
  __syncthreads();
  if (t<128){
    float a = 0.f;
    #pragma unroll
    for (int p=0;p<4;p++) a += spartS[p*128+t];
    q_s[t] = a * (1.f/256.f);          // gctx temp (plain idx, init only)
  }
  __syncthreads();
  if (t<128){ // hidden0 = gctx@Wh.T + bh  (write staggered)
    float a = bh[t];
    const float* wr = Wh + (size_t)t*128;
    for (int k=0;k<128;k++) a += wr[k]*q_s[k];
    h_s[0][H2A(t)] = a;
  }
  { // sv = sum(v)
    float xv = (t<128) ? v[t] : 0.f;
    float tot = dpp_wave_sum(xv);
    if (L==0) red2[w] = tot;
  }
  __syncthreads();
  float sv = 0.f;
  #pragma unroll
  for (int i=0;i<8;i++) sv += red2[i];

  // gi prefetch for step 0
  float gir=0.f, giz=0.f, gin=0.f;
  if (s3==0){
    const float* gp = giall + (size_t)cur*384 + g;
    gir = gp[0]; giz = gp[128]; gin = gp[256];
  }

  for (int step=0; step<255; step++){
    const int par = step & 1;
    const int V   = 255 - step;          // valid count after removing cur
    const int curl = cur - b*256;

    // ---- swap-remove cur's keys column (waves 2-3; reads PRE-update map) ----
    if (t >= 128 && t < 256){
      int r = t - 128;
      int px = node2col_s[curl];
      keys_s[r*KSTRIDE + px] = keys_s[r*KSTRIDE + V];
    }
    if (t == 384) tours_o[b*256+step] = (float)cur;   // wave 6

    // ---- phase A: gh dots + fused GRU -> h_s[par^1] ----
    {
      float a0=0.f,a1=0.f,a2=0.f;
      const float4* hc4 = (const float4*)(h_s[par] + s3*40);
      #pragma unroll
      for (int i=0;i<8;i++){
        float4 hv = hc4[i];
        a0 += dot4(whh4[0][i], hv);
        a1 += dot4(whh4[1][i], hv);
        a2 += dot4(whh4[2][i], hv);
      }
      a0 = quad_sum_dpp(a0);
      a1 = quad_sum_dpp(a1);
      a2 = quad_sum_dpp(a2);
      if (s3==0){
        float r = sigfast(gir + a0 + br);
        float z = sigfast(giz + a1 + bz);
        float n = tanhfast(gin + r*(a2 + bn));
        h_s[par^1][H2A(g)] = (1.f-z)*n + z*h_s[par][H2A(g)];
      }
    }
    __syncthreads();                                   // B1

    // ---- deferred index-map update (wave 7; race-free: all prev-step
    //      combine reads of col2node_s completed before B1) ----
    if (t == 448){
      int px = node2col_s[curl];
      int ln = col2node_s[V];
      col2node_s[px] = ln;
      node2col_s[ln] = px;
    }

    { // qh = relu(h@Wq1.T + bq1)
      float a=0.f;
      const float4* hc4 = (const float4*)(h_s[par^1] + s3*40);
      #pragma unroll
      for (int i=0;i<8;i++) a += dot4(wq14[i], hc4[i]);
      a = quad_sum_dpp(a);
      if (s3==0) qh_s[H2A(g)] = fmaxf(a + b1g, 0.f);
    }
    __syncthreads();                                   // B2

    { // q_raw = qh@Wq2.T + bq2 (PAD16 store) ; per-wave ssq via DPP
      float a=0.f;
      const float4* qc4 = (const float4*)(qh_s + s3*40);
      #pragma unroll
      for (int i=0;i<8;i++) a += dot4(wq24[i], qc4[i]);
      a = quad_sum_dpp(a);
      float qval = a + b2g;
      if (s3==0) q_s[PAD16(g)] = qval;
      float ssp = (s3==0) ? qval*qval : 0.f;
      float tot = dpp_wave_sum(ssp);
      if (L==0) red2[w] = tot;
    }
    __syncthreads();                                   // B3

    // ---- score: wave w -> cols 32w..32w+31 (whole-wave skip when 32w >= V);
    //      rn/eq computed inline (B3b eliminated) ----
    if (32*w < V){
      float ss = 0.f;
      #pragma unroll
      for (int i=0;i<8;i++) ss += red2[i];
      float rn = 1.f / fmaxf(sqrtf(ss), 1e-12f);
      const float* kbase = keys_s + dgrp*16*KSTRIDE + 32*w + oct*4;
      const float* qb    = q_s  + dgrp*20;
      const float* vbase = v_sp + dgrp*20;
      float4 acc = {0.f,0.f,0.f,0.f};
      #pragma unroll
      for (int jj=0;jj<16;jj++){
        float eqj = __builtin_amdgcn_exp2f(qb[jj] * rn * LOG2E2);
        float vj  = vbase[jj];
        float4 K = *(const float4*)(kbase + jj*KSTRIDE);
        float r0 = __builtin_amdgcn_rcpf(fmaf(K.x, eqj, 1.f));
        float r1 = __builtin_amdgcn_rcpf(fmaf(K.y, eqj, 1.f));
        float r2 = __builtin_amdgcn_rcpf(fmaf(K.z, eqj, 1.f));
        float r3 = __builtin_amdgcn_rcpf(fmaf(K.w, eqj, 1.f));
        acc.x = fmaf(vj, r0, acc.x);
        acc.y = fmaf(vj, r1, acc.y);
        acc.z = fmaf(vj, r2, acc.z);
        acc.w = fmaf(vj, r3, acc.w);
      }
      *(float4*)(spartS + dgrp*SSTR + 32*w + oct*4) = acc;
    }
    __syncthreads();                                   // Bs1

    // ---- redundant combine: EVERY wave reduces all 256 cols; every lane
    //      learns argmax + softmax sum -> no Bs2, no tail round-trip ----
    {
      const float* sp = spartS + 4*L;
      float sx=0.f, sy=0.f, sz=0.f, sw=0.f;
      #pragma unroll
      for (int i=0;i<8;i++){
        float4 p = *(const float4*)(sp + i*SSTR);
        sx += p.x; sy += p.y; sz += p.z; sw += p.w;
      }
      int c0 = 4*L;
      float vx = (c0+0 < V) ? sv+sx : -INFINITY;
      float vy = (c0+1 < V) ? sv+sy : -INFINITY;
      float vz = (c0+2 < V) ? sv+sz : -INFINITY;
      float vw = (c0+3 < V) ? sv+sw : -INFINITY;
      float bm = vx; int bc = c0;                 // first-max tie-break
      if (vy > bm){ bm=vy; bc=c0+1; }
      if (vz > bm){ bm=vz; bc=c0+2; }
      if (vw > bm){ bm=vw; bc=c0+3; }
      float m = dpp_wave_max(bm);
      unsigned long long mk = __ballot(bm == m);
      int flane = __ffsll(mk) - 1;                // lowest lane = lowest col
      int besti = __builtin_amdgcn_readlane(bc, flane);
      float es = __builtin_amdgcn_exp2f((vx-m)*LOG2E) + __builtin_amdgcn_exp2f((vy-m)*LOG2E)
               + __builtin_amdgcn_exp2f((vz-m)*LOG2E) + __builtin_amdgcn_exp2f((vw-m)*LOG2E);
      float S = dpp_wave_sum(es);
      cur = b*256 + col2node_s[besti];            // read pre-next-update map
      if (s3==0){   // prefetch next gi (consumed in next phase A)
        const float* gp = giall + (size_t)cur*384 + g;
        gir = gp[0]; giz = gp[128]; gin = gp[256];
      }
      if (t==320) lp_o[b*255+step] = logf(1.f/S + 1e-10f);  // wave 5
    }
    // no barrier: next step's keys-swap/phase-A touch no combine-read state
  }
  if (t==0) tours_o[b*256+255] = (float)cur;

  (void)oct;
}

extern "C" void kernel_launch(void* const* d_in, const int* in_sizes, int n_in,
                              void* d_out, int out_size, void* d_ws, size_t ws_size,
                              hipStream_t stream) {
  const float* emb  = (const float*)d_in[0];
  const int*   startn = (const int*)d_in[1];
  const float* Wq1 = (const float*)d_in[3];  const float* bq1 = (const float*)d_in[4];
  const float* Wq2 = (const float*)d_in[5];  const float* bq2 = (const float*)d_in[6];
  const float* Wk1 = (const float*)d_in[7];  const float* bk1 = (const float*)d_in[8];
  const float* Wk2 = (const float*)d_in[9];  const float* bk2 = (const float*)d_in[10];
  const float* Wih = (const float*)d_in[11]; const float* Whh = (const float*)d_in[12];
  const float* bih = (const float*)d_in[13]; const float* bhh = (const float*)d_in[14];
  const float* v   = (const float*)d_in[15]; const float* Wh  = (const float*)d_in[16];
  const float* bh  = (const float*)d_in[17];

  float* keysE = (float*)d_ws;               // exp(2*keys) TRANSPOSED [128][8192]
  float* giall = keysE + (size_t)TTOT*DD;    // [8192*384]

  float* outp = (float*)d_out;   // tours [32*256] then log_probs [32*255]

  precompute_kernel<<<256, 256, 0, stream>>>(emb, Wk1, bk1, Wk2, bk2, Wih, bih, keysE, giall);
  decode_kernel<<<NGR, 512, 0, stream>>>(emb, keysE, giall, Whh, bhh, Wq1, bq1, Wq2, bq2,
                                         v, Wh, bh, startn, outp, outp + TTOT);
}

// Round 8
// 885.436 us; speedup vs baseline: 2.5800x; 1.0007x over previous
//
#include <hip/hip_runtime.h>
#include <hip/hip_bf16.h>
#include <math.h>

// B=32 graphs, N=256 nodes/graph, D=128.
#define DD   128
#define NPG  256
#define NGR  32
#define TTOT 8192
#define LOG2E  1.4426950408889634f
#define LOG2E2 2.8853900817779268f   // 2*log2(e)
#define KSTRIDE 264                   // LDS floats per transposed key row
#define SSTR    268                   // spartS row stride
#define H2A(j)  ((j) + (((j)>>5)<<3))   // stagger: chunk base -> bank chunk*8
#define PAD16(j) ((j) + (((j)>>4)<<2))  // q/v pad: d -> d + (d>>4)*4
#define WST 132                        // precompute LDS row stride (16B-aligned)

// R20 = R19 decode (byte-identical; measured floor 765-772us) + precompute
// rewrite. Session ledger (decode single-change A/Bs, all vs R12):
//   giall L2-warm 0 | map-in-VGPR +135 (spill) | 9th wave +1400 (spill) |
//   wave5-only tail +38 | px==besti +7. Decode is a phase-locked floor.
// Precompute attack (total-decode ~ 114us): the old mm_tile issued 8 scalar
// ds_read_b32 per k-iter at stride 129 (rows unaligned -> unmergeable), at
// 1 wave/SIMD. New version: stride 132 (aligned rows), ds_read_b128 loads,
// spread output mapping (rows jg+32r, cols ng+8c) -> both read streams
// bank-conflict-free. The FMAs per accumulator stay in STRICT k-order
// (x,y,z,w per float4, k4 ascending) -> bit-identical outputs. The numerics
// contract binds accumulation ORDER, not load width or thread mapping.

__device__ __forceinline__ float dot4(float4 a, float4 b){
  return a.x*b.x + a.y*b.y + a.z*b.z + a.w*b.w;
}
// ---- DPP cross-lane (VALU pipe; keeps ds_bpermute off critical chains) ----
template<int CTRL, int RMASK>
__device__ __forceinline__ float upd_f(float oldv, float x){
  return __int_as_float(__builtin_amdgcn_update_dpp(
      __float_as_int(oldv), __float_as_int(x), CTRL, RMASK, 0xf, false));
}
__device__ __forceinline__ float dpp_xor1(float x){
  return __int_as_float(__builtin_amdgcn_mov_dpp(__float_as_int(x), 0xB1, 0xf, 0xf, false));
}
__device__ __forceinline__ float dpp_xor2(float x){
  return __int_as_float(__builtin_amdgcn_mov_dpp(__float_as_int(x), 0x4E, 0xf, 0xf, false));
}
__device__ __forceinline__ float quad_sum_dpp(float x){
  float s = x + dpp_xor1(x);
  return s + dpp_xor2(s);
}
__device__ __forceinline__ float dpp_wave_sum(float x){
  x += upd_f<0x111,0xf>(0.f, x);   // row_shr:1
  x += upd_f<0x112,0xf>(0.f, x);   // row_shr:2
  x += upd_f<0x114,0xf>(0.f, x);   // row_shr:4
  x += upd_f<0x118,0xf>(0.f, x);   // row_shr:8
  x += upd_f<0x142,0xa>(0.f, x);   // row_bcast15
  x += upd_f<0x143,0xc>(0.f, x);   // row_bcast31
  return __uint_as_float(__builtin_amdgcn_readlane(__float_as_uint(x), 63));
}
__device__ __forceinline__ float dpp_wave_max(float x){
  const float NI = -INFINITY;
  x = fmaxf(x, upd_f<0x111,0xf>(NI, x));
  x = fmaxf(x, upd_f<0x112,0xf>(NI, x));
  x = fmaxf(x, upd_f<0x114,0xf>(NI, x));
  x = fmaxf(x, upd_f<0x118,0xf>(NI, x));
  x = fmaxf(x, upd_f<0x142,0xa>(NI, x));
  x = fmaxf(x, upd_f<0x143,0xc>(NI, x));
  return __uint_as_float(__builtin_amdgcn_readlane(__float_as_uint(x), 63));
}
__device__ __forceinline__ float sigfast(float x){
  return __builtin_amdgcn_rcpf(1.f + __builtin_amdgcn_exp2f(-x*LOG2E));
}
__device__ __forceinline__ float tanhfast(float y){
  return 1.f - 2.f*__builtin_amdgcn_rcpf(1.f + __builtin_amdgcn_exp2f(y*LOG2E2));
}

// ---------------- Kernel 1: parallel precompute (R20 vectorized-load version) ----------------
// keysE[d][n] = exp(2 * l2norm(relu(emb@Wk1.T+bk1)@Wk2.T+bk2)[n][d])  [128][8192] TRANSPOSED
// gi_all = emb@W_ih.T + b_ih                                          [8192,384]
// Per-output accumulation is k=0..127 strictly ascending (the R10 contract);
// loads are float4 but FMAs apply x,y,z,w in order -> bit-identical.

__device__ __forceinline__ void load_w128v(float* Ws, const float* __restrict__ W, int t){
  const float4* src = (const float4*)W;
  #pragma unroll
  for (int m=0;m<16;m++){
    int idx = m*256+t; int r = idx>>5, c4 = idx&31;
    *(float4*)&Ws[r*WST + c4*4] = src[idx];    // 16B-aligned (WST*4 % 16 == 0)
  }
}

// outputs: rows j = jg + 32*r, cols n = ng + 8*c  (jg in [0,32), ng in [0,8))
// W-reads: lanes vary jg -> start banks 4*jg (disjoint b128), broadcast across ng.
// X-reads: lanes vary ng -> start banks 4*ng (disjoint b128), broadcast across jg.
__device__ __forceinline__ void mm_tile4(const float* __restrict__ inS, const float* __restrict__ Ws,
                                         float acc[4][4], int jg, int ng){
  #pragma unroll
  for(int r=0;r<4;r++)
    #pragma unroll
    for(int c=0;c<4;c++) acc[r][c]=0.f;
  #pragma unroll 8
  for (int k4=0;k4<32;k4++){
    float4 wv[4], xv[4];
    #pragma unroll
    for (int r=0;r<4;r++) wv[r] = *(const float4*)&Ws[(jg+32*r)*WST + k4*4];
    #pragma unroll
    for (int c=0;c<4;c++) xv[c] = *(const float4*)&inS[(ng+8*c)*WST + k4*4];
    #pragma unroll
    for (int r=0;r<4;r++)
      #pragma unroll
      for (int c=0;c<4;c++){
        // strict k-order per accumulator: k4*4, +1, +2, +3
        acc[r][c] += wv[r].x*xv[c].x;
        acc[r][c] += wv[r].y*xv[c].y;
        acc[r][c] += wv[r].z*xv[c].z;
        acc[r][c] += wv[r].w*xv[c].w;
      }
  }
}

__global__ __launch_bounds__(256) void precompute_kernel(
    const float* __restrict__ emb,
    const float* __restrict__ Wk1, const float* __restrict__ bk1,
    const float* __restrict__ Wk2, const float* __restrict__ bk2,
    const float* __restrict__ Wih, const float* __restrict__ bih,
    float* __restrict__ keysE, float* __restrict__ giall)
{
  __shared__ __align__(16) float xs[32*WST];
  __shared__ __align__(16) float Ws[128*WST];
  __shared__ __align__(16) float hs[32*WST];
  __shared__ __align__(16) float os[32*WST];
  __shared__ float nrm[32];
  const int t  = threadIdx.x;
  const int n0 = blockIdx.x * 32;
  const int ng = t & 7, jg = t >> 3;     // jg in [0,32): row-group base

  {
    const float4* src = (const float4*)emb + (size_t)n0*32;
    #pragma unroll
    for (int m=0;m<4;m++){
      int idx = m*256+t; int n = idx>>5, c4 = idx&31;
      *(float4*)&xs[n*WST + c4*4] = src[idx];
    }
  }
  load_w128v(Ws, Wk1, t);
  __syncthreads();
  {
    float acc[4][4];
    mm_tile4(xs, Ws, acc, jg, ng);
    #pragma unroll
    for (int r=0;r<4;r++){
      float bb = bk1[jg + 32*r];
      #pragma unroll
      for (int c=0;c<4;c++) hs[(ng+8*c)*WST + jg + 32*r] = fmaxf(acc[r][c]+bb, 0.f);
    }
  }
  __syncthreads();
  load_w128v(Ws, Wk2, t);
  __syncthreads();
  {
    float acc[4][4];
    mm_tile4(hs, Ws, acc, jg, ng);
    #pragma unroll
    for (int r=0;r<4;r++){
      float bb = bk2[jg + 32*r];
      #pragma unroll
      for (int c=0;c<4;c++) os[(ng+8*c)*WST + jg + 32*r] = acc[r][c]+bb;
    }
  }
  __syncthreads();
  if (t<32){
    // serial j-order per node: part of the numerics contract (sum order)
    float ss=0.f;
    for (int j=0;j<128;j++){ float x = os[t*WST+j]; ss += x*x; }
    nrm[t] = fmaxf(sqrtf(ss), 1e-12f);
  }
  __syncthreads();
  // transposed E-keys: keysE[d][n] = exp(2*K)
  #pragma unroll
  for (int m=0;m<16;m++){
    int idx = m*256+t; int nl = idx & 31, d = idx >> 5;
    float kk = os[nl*WST + d] / nrm[nl];
    keysE[(size_t)d*TTOT + n0 + nl] = __builtin_amdgcn_exp2f(kk * LOG2E2);
  }
  for (int c=0;c<3;c++){
    __syncthreads();
    load_w128v(Ws, Wih + c*16384, t);
    __syncthreads();
    float acc[4][4];
    mm_tile4(xs, Ws, acc, jg, ng);
    #pragma unroll
    for (int r=0;r<4;r++){
      float bb = bih[c*128 + jg + 32*r];
      #pragma unroll
      for (int cc=0;cc<4;cc++)
        giall[(size_t)(n0 + ng + 8*cc)*384 + c*128 + jg + 32*r] = acc[r][cc] + bb;
    }
  }
}

// ---------------- Kernel 2: sequential decode ----------------
// BYTE-IDENTICAL to R19/R12 (measured floor; see ledger at top).
// NOTE: the all-waves es/S tail is LOAD-BEARING (R17/R18 isolation: removing
// it from 7 waves costs +38us via phase-locking perturbation). Do not "optimize".

__global__ __launch_bounds__(512, 2) void decode_kernel(
    const float* __restrict__ emb,
    const float* __restrict__ keysE, const float* __restrict__ giall,
    const float* __restrict__ Whh, const float* __restrict__ bhh,
    const float* __restrict__ Wq1, const float* __restrict__ bq1,
    const float* __restrict__ Wq2, const float* __restrict__ bq2,
    const float* __restrict__ v,   const float* __restrict__ Wh,
    const float* __restrict__ bh,  const int* __restrict__ start_nodes,
    float* __restrict__ tours_o, float* __restrict__ lp_o)
{
  __shared__ __align__(16) float keys_s[128*KSTRIDE];  // 132 KB, transposed E-keys
  __shared__ __align__(16) float h_s[2][160];          // staggered (H2A)
  __shared__ __align__(16) float qh_s[160];            // staggered (H2A)
  __shared__ __align__(16) float q_s[160];             // PAD16 (raw q), also gctx scratch
  __shared__ __align__(16) float v_sp[160];            // PAD16 layout, -2*v
  __shared__ __align__(16) float spartS[8*SSTR];       // score partials (+init scratch)
  __shared__ int col2node_s[256], node2col_s[256];
  __shared__ float red2[8];

  const int t = threadIdx.x;
  const int b = blockIdx.x;
  const int g  = t >> 2, s3 = t & 3;   // 128 groups x 4 lanes (matvec)
  const int w  = t >> 6, L  = t & 63;
  const int oct = L & 7, dgrp = L >> 3; // score: col-octet, dim-group

  // register weights: Whh rows g,128+g,256+g (chunk s3*32); Wq1/Wq2 row g
  float4 whh4[3][8], wq14[8], wq24[8];
  {
    const float4* w0  = (const float4*)(Whh + (size_t)(g      )*128 + s3*32);
    const float4* w1  = (const float4*)(Whh + (size_t)(128 + g)*128 + s3*32);
    const float4* w2  = (const float4*)(Whh + (size_t)(256 + g)*128 + s3*32);
    const float4* q1p = (const float4*)(Wq1 + (size_t)g*128 + s3*32);
    const float4* q2p = (const float4*)(Wq2 + (size_t)g*128 + s3*32);
    #pragma unroll
    for (int i=0;i<8;i++){
      whh4[0][i]=w0[i]; whh4[1][i]=w1[i]; whh4[2][i]=w2[i];
      wq14[i]=q1p[i];   wq24[i]=q2p[i];
    }
  }
  const float br = bhh[g], bz = bhh[128+g], bn = bhh[256+g];
  const float b1g = bq1[g], b2g = bq2[g];

  if (t<128) v_sp[PAD16(t)] = -2.f * v[t];
  if (t<256){ col2node_s[t] = t; node2col_s[t] = t; }
  { // stage transposed E-keys: coalesced per d-row
    #pragma unroll
    for (int m=0;m<16;m++){
      int idx = m*512 + t; int d = idx>>6, q = idx&63;
      *(float4*)(keys_s + d*KSTRIDE + q*4) =
        *(const float4*)(keysE + (size_t)d*TTOT + b*256 + q*4);
    }
  }
  { // graph-context partial sums (4 parts x 64 nodes)
    int d = t & 127, part = t >> 7;
    float a = 0.f;
    const float* base = emb + (size_t)(b*256 + part*64)*128 + d;
    for (int i=0;i<64;i++) a += base[(size_t)i*128];
    spartS[part*128+d] = a;
  }
  int cur = start_nodes[b];
  __syncthreads();
  if (t<128){
    float a = 0.f;
    #pragma unroll
    for (int p=0;p<4;p++) a += spartS[p*128+t];
    q_s[t] = a * (1.f/256.f);          // gctx temp (plain idx, init only)
  }
  __syncthreads();
  if (t<128){ // hidden0 = gctx@Wh.T + bh  (write staggered)
    float a = bh[t];
    const float* wr = Wh + (size_t)t*128;
    for (int k=0;k<128;k++) a += wr[k]*q_s[k];
    h_s[0][H2A(t)] = a;
  }
  { // sv = sum(v)
    float xv = (t<128) ? v[t] : 0.f;
    float tot = dpp_wave_sum(xv);
    if (L==0) red2[w] = tot;
  }
  __syncthreads();
  float sv = 0.f;
  #pragma unroll
  for (int i=0;i<8;i++) sv += red2[i];

  // gi prefetch for step 0
  float gir=0.f, giz=0.f, gin=0.f;
  if (s3==0){
    const float* gp = giall + (size_t)cur*384 + g;
    gir = gp[0]; giz = gp[128]; gin = gp[256];
  }

  for (int step=0; step<255; step++){
    const int par = step & 1;
    const int V   = 255 - step;          // valid count after removing cur
    const int curl = cur - b*256;

    // ---- swap-remove cur's keys column (waves 2-3; reads PRE-update map) ----
    if (t >= 128 && t < 256){
      int r = t - 128;
      int px = node2col_s[curl];
      keys_s[r*KSTRIDE + px] = keys_s[r*KSTRIDE + V];
    }
    if (t == 384) tours_o[b*256+step] = (float)cur;   // wave 6

    // ---- phase A: gh dots + fused GRU -> h_s[par^1] ----
    {
      float a0=0.f,a1=0.f,a2=0.f;
      const float4* hc4 = (const float4*)(h_s[par] + s3*40);
      #pragma unroll
      for (int i=0;i<8;i++){
        float4 hv = hc4[i];
        a0 += dot4(whh4[0][i], hv);
        a1 += dot4(whh4[1][i], hv);
        a2 += dot4(whh4[2][i], hv);
      }
      a0 = quad_sum_dpp(a0);
      a1 = quad_sum_dpp(a1);
      a2 = quad_sum_dpp(a2);
      if (s3==0){
        float r = sigfast(gir + a0 + br);
        float z = sigfast(giz + a1 + bz);
        float n = tanhfast(gin + r*(a2 + bn));
        h_s[par^1][H2A(g)] = (1.f-z)*n + z*h_s[par][H2A(g)];
      }
    }
    __syncthreads();                                   // B1

    // ---- deferred index-map update (wave 7; race-free: all prev-step
    //      combine reads of col2node_s completed before B1) ----
    if (t == 448){
      int px = node2col_s[curl];
      int ln = col2node_s[V];
      col2node_s[px] = ln;
      node2col_s[ln] = px;
    }

    { // qh = relu(h@Wq1.T + bq1)
      float a=0.f;
      const float4* hc4 = (const float4*)(h_s[par^1] + s3*40);
      #pragma unroll
      for (int i=0;i<8;i++) a += dot4(wq14[i], hc4[i]);
      a = quad_sum_dpp(a);
      if (s3==0) qh_s[H2A(g)] = fmaxf(a + b1g, 0.f);
    }
    __syncthreads();                                   // B2

    { // q_raw = qh@Wq2.T + bq2 (PAD16 store) ; per-wave ssq via DPP
      float a=0.f;
      const float4* qc4 = (const float4*)(qh_s + s3*40);
      #pragma unroll
      for (int i=0;i<8;i++) a += dot4(wq24[i], qc4[i]);
      a = quad_sum_dpp(a);
      float qval = a + b2g;
      if (s3==0) q_s[PAD16(g)] = qval;
      float ssp = (s3==0) ? qval*qval : 0.f;
      float tot = dpp_wave_sum(ssp);
      if (L==0) red2[w] = tot;
    }
    __syncthreads();                                   // B3

    // ---- score: wave w -> cols 32w..32w+31 (whole-wave skip when 32w >= V);
    //      rn/eq computed inline (B3b eliminated) ----
    if (32*w < V){
      float ss = 0.f;
      #pragma unroll
      for (int i=0;i<8;i++) ss += red2[i];
      float rn = 1.f / fmaxf(sqrtf(ss), 1e-12f);
      const float* kbase = keys_s + dgrp*16*KSTRIDE + 32*w + oct*4;
      const float* qb    = q_s  + dgrp*20;
      const float* vbase = v_sp + dgrp*20;
      float4 acc = {0.f,0.f,0.f,0.f};
      #pragma unroll
      for (int jj=0;jj<16;jj++){
        float eqj = __builtin_amdgcn_exp2f(qb[jj] * rn * LOG2E2);
        float vj  = vbase[jj];
        float4 K = *(const float4*)(kbase + jj*KSTRIDE);
        float r0 = __builtin_amdgcn_rcpf(fmaf(K.x, eqj, 1.f));
        float r1 = __builtin_amdgcn_rcpf(fmaf(K.y, eqj, 1.f));
        float r2 = __builtin_amdgcn_rcpf(fmaf(K.z, eqj, 1.f));
        float r3 = __builtin_amdgcn_rcpf(fmaf(K.w, eqj, 1.f));
        acc.x = fmaf(vj, r0, acc.x);
        acc.y = fmaf(vj, r1, acc.y);
        acc.z = fmaf(vj, r2, acc.z);
        acc.w = fmaf(vj, r3, acc.w);
      }
      *(float4*)(spartS + dgrp*SSTR + 32*w + oct*4) = acc;
    }
    __syncthreads();                                   // Bs1

    // ---- redundant combine: EVERY wave reduces all 256 cols; every lane
    //      learns argmax + softmax sum -> no Bs2, no tail round-trip ----
    {
      const float* sp = spartS + 4*L;
      float sx=0.f, sy=0.f, sz=0.f, sw=0.f;
      #pragma unroll
      for (int i=0;i<8;i++){
        float4 p = *(const float4*)(sp + i*SSTR);
        sx += p.x; sy += p.y; sz += p.z; sw += p.w;
      }
      int c0 = 4*L;
      float vx = (c0+0 < V) ? sv+sx : -INFINITY;
      float vy = (c0+1 < V) ? sv+sy : -INFINITY;
      float vz = (c0+2 < V) ? sv+sz : -INFINITY;
      float vw = (c0+3 < V) ? sv+sw : -INFINITY;
      float bm = vx; int bc = c0;                 // first-max tie-break
      if (vy > bm){ bm=vy; bc=c0+1; }
      if (vz > bm){ bm=vz; bc=c0+2; }
      if (vw > bm){ bm=vw; bc=c0+3; }
      float m = dpp_wave_max(bm);
      unsigned long long mk = __ballot(bm == m);
      int flane = __ffsll(mk) - 1;                // lowest lane = lowest col
      int besti = __builtin_amdgcn_readlane(bc, flane);
      float es = __builtin_amdgcn_exp2f((vx-m)*LOG2E) + __builtin_amdgcn_exp2f((vy-m)*LOG2E)
               + __builtin_amdgcn_exp2f((vz-m)*LOG2E) + __builtin_amdgcn_exp2f((vw-m)*LOG2E);
      float S = dpp_wave_sum(es);
      cur = b*256 + col2node_s[besti];            // read pre-next-update map
      if (s3==0){   // prefetch next gi (consumed in next phase A)
        const float* gp = giall + (size_t)cur*384 + g;
        gir = gp[0]; giz = gp[128]; gin = gp[256];
      }
      if (t==320) lp_o[b*255+step] = logf(1.f/S + 1e-10f);  // wave 5
    }
    // no barrier: next step's keys-swap/phase-A touch no combine-read state
  }
  if (t==0) tours_o[b*256+255] = (float)cur;

  (void)oct;
}

extern "C" void kernel_launch(void* const* d_in, const int* in_sizes, int n_in,
                              void* d_out, int out_size, void* d_ws, size_t ws_size,
                              hipStream_t stream) {
  const float* emb  = (const float*)d_in[0];
  const int*   startn = (const int*)d_in[1];
  const float* Wq1 = (const float*)d_in[3];  const float* bq1 = (const float*)d_in[4];
  const float* Wq2 = (const float*)d_in[5];  const float* bq2 = (const float*)d_in[6];
  const float* Wk1 = (const float*)d_in[7];  const float* bk1 = (const float*)d_in[8];
  const float* Wk2 = (const float*)d_in[9];  const float* bk2 = (const float*)d_in[10];
  const float* Wih = (const float*)d_in[11]; const float* Whh = (const float*)d_in[12];
  const float* bih = (const float*)d_in[13]; const float* bhh = (const float*)d_in[14];
  const float* v   = (const float*)d_in[15]; const float* Wh  = (const float*)d_in[16];
  const float* bh  = (const float*)d_in[17];

  float* keysE = (float*)d_ws;               // exp(2*keys) TRANSPOSED [128][8192]
  float* giall = keysE + (size_t)TTOT*DD;    // [8192*384]

  float* outp = (float*)d_out;   // tours [32*256] then log_probs [32*255]

  precompute_kernel<<<256, 256, 0, stream>>>(emb, Wk1, bk1, Wk2, bk2, Wih, bih, keysE, giall);
  decode_kernel<<<NGR, 512, 0, stream>>>(emb, keysE, giall, Whh, bhh, Wq1, bq1, Wq2, bq2,
                                         v, Wh, bh, startn, outp, outp + TTOT);
}